// Round 1
// baseline (831.045 us; speedup 1.0000x reference)
//
#include <hip/hip_runtime.h>

// cWCT: out = Ls·inv(Lc)·(xc − c_mean) + s_mean  =  T·xc + bias
// B=8, N=256, L=16384. fp32 in/out; bf16 MFMA for the big GEMMs.
// Round 3: k_chol made fully LDS-resident — the packed lower triangle
// (131.6 KB) lives in LDS for the whole factorization; global traffic is
// one read of gram and one write of the result. Removes the per-panel
// global stage/writeback and the ~25K scattered global RMWs per panel
// that made the old k_chol latency-bound (VALUBusy 0.6%).

#define BATCH 8
#define NF    256
#define LSP   16384
#define EPS_J 2e-5f

typedef float f32x4  __attribute__((ext_vector_type(4)));
typedef short bf16x8 __attribute__((ext_vector_type(8)));
typedef short short4v __attribute__((ext_vector_type(4)));

__device__ __forceinline__ short f2bf(float f) {
    unsigned u = __float_as_uint(f);
    u = (u + 0x7FFFu + ((u >> 16) & 1u)) >> 16;   // RNE to bf16
    return (short)u;
}

// ---------------------------------------------------------------------------
// K1: batched syrk  gram[m] += A·Aᵀ (bf16 MFMA, split-K) + fp32 row sums.
// grid (splitk=16, m=16), 1024 threads. (unchanged — proven)
// ---------------------------------------------------------------------------
__global__ __launch_bounds__(1024) void k_cov(const float* __restrict__ cont,
                                              const float* __restrict__ styl,
                                              float* __restrict__ gram,
                                              float* __restrict__ rowsum) {
    const int kc = blockIdx.x;
    const int m  = blockIdx.y;
    const float* __restrict__ src = (m < BATCH)
        ? cont + (size_t)m * NF * LSP
        : styl + (size_t)(m - BATCH) * NF * LSP;

    __shared__ short lds[256][72];

    const int t    = threadIdx.x;
    const int lane = t & 63;
    const int w    = t >> 6;
    const int wi   = (w & 3) * 64;
    const int wj   = (w >> 2) * 64;
    const int fr   = t >> 4;
    const int fc   = (t & 15) * 4;

    f32x4 acc[4][4];
    #pragma unroll
    for (int i = 0; i < 4; ++i)
        #pragma unroll
        for (int j = 0; j < 4; ++j) { f32x4 z = {0.f,0.f,0.f,0.f}; acc[i][j] = z; }

    float rs[4] = {0.f, 0.f, 0.f, 0.f};

    const size_t kbase = (size_t)kc * 1024;
    float4 pre[4];
    #pragma unroll
    for (int j = 0; j < 4; ++j)
        pre[j] = *(const float4*)(src + (size_t)(fr + j * 64) * LSP + kbase + fc);

    for (int step = 0; step < 16; ++step) {
        __syncthreads();
        #pragma unroll
        for (int j = 0; j < 4; ++j) {
            float4 v = pre[j];
            rs[j] += v.x + v.y + v.z + v.w;
            short4v b4 = { f2bf(v.x), f2bf(v.y), f2bf(v.z), f2bf(v.w) };
            *(short4v*)&lds[fr + j * 64][fc] = b4;
        }
        __syncthreads();
        if (step < 15) {
            const size_t k0n = kbase + (size_t)(step + 1) * 64;
            #pragma unroll
            for (int j = 0; j < 4; ++j)
                pre[j] = *(const float4*)(src + (size_t)(fr + j * 64) * LSP + k0n + fc);
        }
        #pragma unroll
        for (int ks = 0; ks < 2; ++ks) {
            const int kk   = ks * 32 + (lane >> 4) * 8;
            const int rsel = lane & 15;
            bf16x8 af[4], bfv[4];
            #pragma unroll
            for (int mi = 0; mi < 4; ++mi)
                af[mi] = *(const bf16x8*)&lds[wi + mi * 16 + rsel][kk];
            #pragma unroll
            for (int nj = 0; nj < 4; ++nj)
                bfv[nj] = *(const bf16x8*)&lds[wj + nj * 16 + rsel][kk];
            #pragma unroll
            for (int mi = 0; mi < 4; ++mi)
                #pragma unroll
                for (int nj = 0; nj < 4; ++nj)
                    acc[mi][nj] = __builtin_amdgcn_mfma_f32_16x16x32_bf16(
                        af[mi], bfv[nj], acc[mi][nj], 0, 0, 0);
        }
    }

    float* rsm = rowsum + m * NF;
    #pragma unroll
    for (int j = 0; j < 4; ++j) {
        float v = rs[j];
        v += __shfl_xor(v, 1);
        v += __shfl_xor(v, 2);
        v += __shfl_xor(v, 4);
        v += __shfl_xor(v, 8);
        if ((lane & 15) == 0) atomicAdd(rsm + fr + j * 64, v);
    }

    float* g = gram + (size_t)m * NF * NF;
    const int rowb = (lane >> 4) * 4;
    const int colb = lane & 15;
    #pragma unroll
    for (int mi = 0; mi < 4; ++mi)
        #pragma unroll
        for (int nj = 0; nj < 4; ++nj) {
            const int row = wi + mi * 16 + rowb;
            const int col = wj + nj * 16 + colb;
            #pragma unroll
            for (int r = 0; r < 4; ++r)
                atomicAdd(g + (size_t)(row + r) * NF + col, acc[mi][nj][r]);
        }
}

// ---------------------------------------------------------------------------
// K2: cov formation + full panel Cholesky, entirely LDS-resident.
// One block (1024 thr, 16 waves) per matrix. Packed lower triangle
// (row r at r*(r+1)/2, 131.6 KB) in LDS; global traffic = 1 read of gram
// + 1 write of the result (style: Lg lower; content: LcT transposed).
// ---------------------------------------------------------------------------
__global__ __launch_bounds__(1024) void k_chol(float* __restrict__ Lg_all,
                                               const float* __restrict__ rowsum,
                                               float* __restrict__ LcT_all,
                                               float* __restrict__ mean_all) {
    const int m = blockIdx.x;
    float* __restrict__ Lg  = Lg_all + (size_t)m * NF * NF;   // aliases gram[m]
    float* __restrict__ LcT = (m < BATCH) ? (LcT_all + (size_t)m * NF * NF) : nullptr;

    __shared__ float Lt[32896];     // packed lower triangle (131584 B)
    __shared__ float Sm[NF];
    __shared__ float Db[32][33];    // factored diag block (broadcast for trsm)
    __shared__ float rDd[32];       // 1/diag
    __shared__ short Pb[224][40];   // solved panel, bf16, 80B rows (16B-aligned)

    const int t    = threadIdx.x;
    const int lane = t & 63;
    const int wv   = t >> 6;

    if (t < NF) {
        float s = rowsum[m * NF + t];
        Sm[t] = s;
        mean_all[m * NF + t] = s * (1.f / (float)LSP);
    }
    __syncthreads();

    // cov = (G - S·Sᵀ/L)/(L-1) + eps·I, built straight into packed LDS
    const float invLn  = 1.f / (float)LSP;
    const float invLm1 = 1.f / (float)(LSP - 1);
    for (int idx = t; idx < NF * NF; idx += 1024) {
        const int r = idx >> 8, c = idx & 255;
        if (c <= r) {
            float v = (Lg[idx] - Sm[r] * Sm[c] * invLn) * invLm1;
            if (c == r) v += EPS_J;
            Lt[((r * (r + 1)) >> 1) + c] = v;
        }
    }
    __syncthreads();

    for (int jb = 0; jb < NF; jb += 32) {
        const int R0 = jb + 32;
        const int R  = NF - R0;      // rows below the diag block (224..0)

        // wave 0, lanes 0..31: factor the 32x32 diag block in registers
        if (t < 32) {
            const int r = t;
            const int rbase = (((jb + r) * (jb + r + 1)) >> 1) + jb;
            float a[32];
            #pragma unroll
            for (int c = 0; c < 32; ++c)
                a[c] = (c <= r) ? Lt[rbase + c] : 0.f;
            #pragma unroll
            for (int j = 0; j < 32; ++j) {
                const float d   = __shfl(a[j], j);
                const float sq  = sqrtf(d);
                const float inv = 1.f / sq;
                const float lj  = a[j] * inv;   // L[r][j] for r>=j (r==j -> sq)
                a[j] = lj;
                #pragma unroll
                for (int c = j + 1; c < 32; ++c)
                    a[c] -= lj * __shfl(lj, c);     // -= L[r][j]*L[c][j]
                if (r == 0) rDd[j] = inv;
            }
            #pragma unroll
            for (int c = 0; c < 32; ++c)
                if (c <= r) {
                    const float v = a[c];
                    Lt[rbase + c] = v;
                    Db[r][c] = v;
                }
        }
        __syncthreads();   // Db, rDd ready

        // trsm: one thread per row below diag, 32-step register solve (in LDS)
        if (t < R) {
            const int row  = R0 + t;
            const int base = ((row * (row + 1)) >> 1) + jb;
            float x[32];
            #pragma unroll
            for (int c = 0; c < 32; ++c) x[c] = Lt[base + c];
            #pragma unroll
            for (int c = 0; c < 32; ++c) {
                float acc = x[c];
                #pragma unroll
                for (int k = 0; k < c; ++k) acc -= x[k] * Db[c][k];
                x[c] = acc * rDd[c];
            }
            #pragma unroll
            for (int c = 0; c < 32; ++c) {
                Lt[base + c] = x[c];
                Pb[t][c]  = f2bf(x[c]);
            }
        }
        __syncthreads();   // solved panel in Lt + Pb ready

        // trailing syrk via MFMA: C[r][c] -= Σ_j P[r][j]·P[c][j], 16x16 tiles,
        // read-modify-write entirely in LDS
        if (R > 0) {
            const int nt  = R >> 4;
            const int ntt = nt * (nt + 1) / 2;
            for (int tt = wv; tt < ntt; tt += 16) {
                int tr = (int)((sqrtf(8.f * (float)tt + 1.f) - 1.f) * 0.5f);
                while ((tr + 1) * (tr + 2) / 2 <= tt) ++tr;
                while (tr * (tr + 1) / 2 > tt) --tr;
                const int tc = tt - tr * (tr + 1) / 2;
                const int r0 = tr * 16, c0 = tc * 16;   // relative to R0
                bf16x8 af  = *(const bf16x8*)&Pb[r0 + (lane & 15)][(lane >> 4) * 8];
                bf16x8 bfv = *(const bf16x8*)&Pb[c0 + (lane & 15)][(lane >> 4) * 8];
                f32x4 accv = {0.f, 0.f, 0.f, 0.f};
                accv = __builtin_amdgcn_mfma_f32_16x16x32_bf16(af, bfv, accv, 0, 0, 0);
                const int col  = R0 + c0 + (lane & 15);
                const int rowb = R0 + r0 + (lane >> 4) * 4;
                #pragma unroll
                for (int rg = 0; rg < 4; ++rg) {
                    const int row = rowb + rg;
                    if (col <= row)
                        Lt[((row * (row + 1)) >> 1) + col] -= accv[rg];
                }
            }
        }
        __syncthreads();   // trailing updated before next panel
    }

    // epilogue: one-shot write-out
    if (LcT) {
        // content: write transposed full lower (LcT[c][r] = L[r][c], r >= c);
        // k_solveT reads LcT rows (= Lc columns) — coalesced here.
        for (int idx = t; idx < NF * NF; idx += 1024) {
            const int cc = idx >> 8, rr = idx & 255;
            if (rr >= cc) LcT[idx] = Lt[((rr * (rr + 1)) >> 1) + cc];
        }
    } else {
        // style: write lower triangle back into Lg (= Ls); k_solveT reads
        // only Ls[i][j] for j <= i, so the stale upper half is never seen.
        for (int idx = t; idx < NF * NF; idx += 1024) {
            const int r = idx >> 8, c = idx & 255;
            if (c <= r) Lg[idx] = Lt[((r * (r + 1)) >> 1) + c];
        }
    }
}

// ---------------------------------------------------------------------------
// K3: solve T·Lc = Ls per row of T (T lower-triangular), write Tbf (bf16)
// and bias[i] = s_mean[i] − Σ_k T[i,k]·c_mean[k]. One wave per (b, i).
// grid 512 x 256 thr (4 waves). Lc read via LcT (contiguous columns).
// ---------------------------------------------------------------------------
__global__ __launch_bounds__(256) void k_solveT(const float* __restrict__ Lg_all,
                                                const float* __restrict__ LcT_all,
                                                const float* __restrict__ mean_all,
                                                short* __restrict__ Tbf,
                                                float* __restrict__ bias) {
    const int lane = threadIdx.x & 63;
    const int wv   = threadIdx.x >> 6;
    const int task = blockIdx.x * 4 + wv;
    const int b    = task >> 8;
    const int i    = task & 255;
    const float* __restrict__ Ls  = Lg_all + (size_t)(BATCH + b) * NF * NF + (size_t)i * NF;
    const float* __restrict__ LcT = LcT_all + (size_t)b * NF * NF;

    __shared__ float vbuf[4][NF];
    float* vb = vbuf[wv];
    for (int k = lane; k < NF; k += 64) vb[k] = 0.f;

    int j = i;
    for (; j >= 1; j -= 2) {
        const float* __restrict__ r0 = LcT + (size_t)j * NF;        // Lc[k][j]
        const float* __restrict__ r1 = r0 - NF;                     // Lc[k][j-1]
        float s0 = 0.f, s1 = 0.f;
        for (int k = j + 1 + lane; k <= i; k += 64) {
            const float tk = vb[k];
            s0 += tk * r0[k];
            s1 += tk * r1[k];
        }
        #pragma unroll
        for (int mm = 32; mm >= 1; mm >>= 1) {
            s0 += __shfl_xor(s0, mm);
            s1 += __shfl_xor(s1, mm);
        }
        if (lane == 0) {
            const float tj  = (Ls[j] - s0) / r0[j];
            const float tjm = (Ls[j - 1] - s1 - tj * r1[j]) / r1[j - 1];
            vb[j]     = tj;
            vb[j - 1] = tjm;
        }
    }
    if (j == 0) {
        const float* __restrict__ r0 = LcT;
        float s0 = 0.f;
        for (int k = 1 + lane; k <= i; k += 64) s0 += vb[k] * r0[k];
        #pragma unroll
        for (int mm = 32; mm >= 1; mm >>= 1) s0 += __shfl_xor(s0, mm);
        if (lane == 0) vb[0] = (Ls[0] - s0) / r0[0];
    }

    // bias[i] = s_mean[i] − Σ T[i,k]·c_mean[k]
    const float* __restrict__ cm  = mean_all + b * NF;
    const float* __restrict__ smn = mean_all + (BATCH + b) * NF;
    float dot = 0.f;
    for (int k = lane; k < NF; k += 64) dot += vb[k] * cm[k];
    #pragma unroll
    for (int mm = 32; mm >= 1; mm >>= 1) dot += __shfl_xor(dot, mm);
    if (lane == 0) bias[b * NF + i] = smn[i] - dot;

    short* __restrict__ Tr = Tbf + (size_t)b * NF * NF + (size_t)i * NF;
    const int k4 = lane * 4;
    short4v o = { f2bf(vb[k4]), f2bf(vb[k4 + 1]), f2bf(vb[k4 + 2]), f2bf(vb[k4 + 3]) };
    *(short4v*)&Tr[k4] = o;
}

// ---------------------------------------------------------------------------
// K4: out = T·xc + bias. bf16 MFMA, tile 256(i) x 64(l), K=256.
// grid (256 l-tiles, 8 batches), 256 thr (4 waves of 64x64).
// ---------------------------------------------------------------------------
__global__ __launch_bounds__(256) void k_out(const float* __restrict__ cont,
                                             const short* __restrict__ Tbf,
                                             const float* __restrict__ bias,
                                             float* __restrict__ out) {
    const int b  = blockIdx.y;
    const int l0 = blockIdx.x * 64;
    const float* __restrict__ X  = cont + (size_t)b * NF * LSP;
    const short* __restrict__ Tb = Tbf + (size_t)b * NF * NF;
    float* __restrict__ O = out + (size_t)b * NF * LSP;

    __shared__ short a_s[256][72];
    __shared__ short b_s[64][72];
    __shared__ float bias_s[NF];

    const int t    = threadIdx.x;
    const int lane = t & 63;
    const int w    = t >> 6;

    bias_s[t] = bias[b * NF + t];

    f32x4 acc[4][4];
    #pragma unroll
    for (int i = 0; i < 4; ++i)
        #pragma unroll
        for (int j = 0; j < 4; ++j) { f32x4 z = {0.f,0.f,0.f,0.f}; acc[i][j] = z; }

    const int kb = (t >> 4) * 4;
    const int lb = (t & 15) * 4;
    const int fr = t >> 4;
    const int fc = (t & 15) * 4;

    float4 xr[4];
    #pragma unroll
    for (int r = 0; r < 4; ++r)
        xr[r] = *(const float4*)(X + (size_t)(kb + r) * LSP + l0 + lb);

    for (int step = 0; step < 4; ++step) {
        const int k0 = step * 64;
        __syncthreads();
        #pragma unroll
        for (int s2 = 0; s2 < 16; ++s2) {
            const int row = fr + s2 * 16;
            *(short4v*)&a_s[row][fc] = *(const short4v*)(Tb + (size_t)row * NF + k0 + fc);
        }
        {
            short4v c0v = { f2bf(xr[0].x), f2bf(xr[1].x), f2bf(xr[2].x), f2bf(xr[3].x) };
            short4v c1v = { f2bf(xr[0].y), f2bf(xr[1].y), f2bf(xr[2].y), f2bf(xr[3].y) };
            short4v c2v = { f2bf(xr[0].z), f2bf(xr[1].z), f2bf(xr[2].z), f2bf(xr[3].z) };
            short4v c3v = { f2bf(xr[0].w), f2bf(xr[1].w), f2bf(xr[2].w), f2bf(xr[3].w) };
            *(short4v*)&b_s[lb + 0][kb] = c0v;
            *(short4v*)&b_s[lb + 1][kb] = c1v;
            *(short4v*)&b_s[lb + 2][kb] = c2v;
            *(short4v*)&b_s[lb + 3][kb] = c3v;
        }
        __syncthreads();
        if (step < 3) {
            const int k0n = k0 + 64;
            #pragma unroll
            for (int r = 0; r < 4; ++r)
                xr[r] = *(const float4*)(X + (size_t)(k0n + kb + r) * LSP + l0 + lb);
        }
        #pragma unroll
        for (int ks = 0; ks < 2; ++ks) {
            const int kk   = ks * 32 + (lane >> 4) * 8;
            const int rsel = lane & 15;
            bf16x8 af[4], bfv[4];
            #pragma unroll
            for (int mi = 0; mi < 4; ++mi)
                af[mi] = *(const bf16x8*)&a_s[w * 64 + mi * 16 + rsel][kk];
            #pragma unroll
            for (int nj = 0; nj < 4; ++nj)
                bfv[nj] = *(const bf16x8*)&b_s[nj * 16 + rsel][kk];
            #pragma unroll
            for (int mi = 0; mi < 4; ++mi)
                #pragma unroll
                for (int nj = 0; nj < 4; ++nj)
                    acc[mi][nj] = __builtin_amdgcn_mfma_f32_16x16x32_bf16(
                        af[mi], bfv[nj], acc[mi][nj], 0, 0, 0);
        }
    }

    #pragma unroll
    for (int mi = 0; mi < 4; ++mi) {
        const int row = w * 64 + mi * 16 + (lane >> 4) * 4;
        #pragma unroll
        for (int nj = 0; nj < 4; ++nj) {
            const int col = l0 + nj * 16 + (lane & 15);
            #pragma unroll
            for (int r = 0; r < 4; ++r)
                O[(size_t)(row + r) * LSP + col] = acc[mi][nj][r] + bias_s[row + r];
        }
    }
}

// ---------------------------------------------------------------------------
extern "C" void kernel_launch(void* const* d_in, const int* in_sizes, int n_in,
                              void* d_out, int out_size, void* d_ws, size_t ws_size,
                              hipStream_t stream) {
    (void)in_sizes; (void)n_in; (void)out_size; (void)ws_size;
    const float* cont = (const float*)d_in[0];
    const float* styl = (const float*)d_in[1];
    float* out = (float*)d_out;

    float* ws       = (float*)d_ws;
    float* gram     = ws;                         // 16*65536 f32 — reused as Lg
    float* rowsum   = gram + 16 * 65536;          // 16*256
    float* mean_all = rowsum + 4096;              // 16*256
    float* bias     = mean_all + 4096;            // 8*256
    float* LcT      = bias + 2048;                // 8*65536 f32 (2 MB)
    short* Tbf      = (short*)(LcT + 8 * 65536);  // 8*65536 bf16 (1 MB)

    // zero gram + rowsum (atomic accumulation targets)
    hipMemsetAsync(gram, 0, (size_t)(16 * 65536 + 4096) * sizeof(float), stream);

    k_cov   <<<dim3(16, 16), 1024, 0, stream>>>(cont, styl, gram, rowsum);
    k_chol  <<<16,           1024, 0, stream>>>(gram, rowsum, LcT, mean_all);
    k_solveT<<<512,          256,  0, stream>>>(gram, LcT, mean_all, Tbf, bias);
    k_out   <<<dim3(256, 8), 256,  0, stream>>>(cont, Tbf, bias, out);
}

// Round 2
// 720.544 us; speedup vs baseline: 1.1534x; 1.1534x over previous
//
#include <hip/hip_runtime.h>

// cWCT: out = Ls·inv(Lc)·(xc − c_mean) + s_mean  =  T·xc + bias
// B=8, N=256, L=16384. fp32 in/out; bf16 MFMA for the big GEMMs.
// Round 4: k_chol critical-path rewrite. Round-3 post-mortem showed the
// LDS-residency change was null -> bottleneck is the serial factor path:
//  (A) diag factor: now single dependent shuffle/step (shuffle unscaled
//      column, divide by d) + v_rcp/v_rsq instead of sqrtf + IEEE div.
//  (B) trsm (was 4 waves x 496 broadcast LDS reads x 8 panels + 496-FMA
//      serial chains): replaced by W = inv(Db) on wave 0, then the panel
//      solve X = Pan·W^T as 3 MFMAs/tile in split-bf16 (hi/lo) -> ~fp32
//      precision. Waves 1..15 prefetch+convert Pan fragments during (A).

#define BATCH 8
#define NF    256
#define LSP   16384
#define EPS_J 2e-5f

typedef float f32x4  __attribute__((ext_vector_type(4)));
typedef short bf16x8 __attribute__((ext_vector_type(8)));
typedef short short4v __attribute__((ext_vector_type(4)));

__device__ __forceinline__ short f2bf(float f) {
    unsigned u = __float_as_uint(f);
    u = (u + 0x7FFFu + ((u >> 16) & 1u)) >> 16;   // RNE to bf16
    return (short)u;
}
__device__ __forceinline__ float bf2f(short s) {
    return __uint_as_float(((unsigned)(unsigned short)s) << 16);
}

// ---------------------------------------------------------------------------
// K1: batched syrk  gram[m] += A·Aᵀ (bf16 MFMA, split-K) + fp32 row sums.
// grid (splitk=16, m=16), 1024 threads. (unchanged — proven)
// ---------------------------------------------------------------------------
__global__ __launch_bounds__(1024) void k_cov(const float* __restrict__ cont,
                                              const float* __restrict__ styl,
                                              float* __restrict__ gram,
                                              float* __restrict__ rowsum) {
    const int kc = blockIdx.x;
    const int m  = blockIdx.y;
    const float* __restrict__ src = (m < BATCH)
        ? cont + (size_t)m * NF * LSP
        : styl + (size_t)(m - BATCH) * NF * LSP;

    __shared__ short lds[256][72];

    const int t    = threadIdx.x;
    const int lane = t & 63;
    const int w    = t >> 6;
    const int wi   = (w & 3) * 64;
    const int wj   = (w >> 2) * 64;
    const int fr   = t >> 4;
    const int fc   = (t & 15) * 4;

    f32x4 acc[4][4];
    #pragma unroll
    for (int i = 0; i < 4; ++i)
        #pragma unroll
        for (int j = 0; j < 4; ++j) { f32x4 z = {0.f,0.f,0.f,0.f}; acc[i][j] = z; }

    float rs[4] = {0.f, 0.f, 0.f, 0.f};

    const size_t kbase = (size_t)kc * 1024;
    float4 pre[4];
    #pragma unroll
    for (int j = 0; j < 4; ++j)
        pre[j] = *(const float4*)(src + (size_t)(fr + j * 64) * LSP + kbase + fc);

    for (int step = 0; step < 16; ++step) {
        __syncthreads();
        #pragma unroll
        for (int j = 0; j < 4; ++j) {
            float4 v = pre[j];
            rs[j] += v.x + v.y + v.z + v.w;
            short4v b4 = { f2bf(v.x), f2bf(v.y), f2bf(v.z), f2bf(v.w) };
            *(short4v*)&lds[fr + j * 64][fc] = b4;
        }
        __syncthreads();
        if (step < 15) {
            const size_t k0n = kbase + (size_t)(step + 1) * 64;
            #pragma unroll
            for (int j = 0; j < 4; ++j)
                pre[j] = *(const float4*)(src + (size_t)(fr + j * 64) * LSP + k0n + fc);
        }
        #pragma unroll
        for (int ks = 0; ks < 2; ++ks) {
            const int kk   = ks * 32 + (lane >> 4) * 8;
            const int rsel = lane & 15;
            bf16x8 af[4], bfv[4];
            #pragma unroll
            for (int mi = 0; mi < 4; ++mi)
                af[mi] = *(const bf16x8*)&lds[wi + mi * 16 + rsel][kk];
            #pragma unroll
            for (int nj = 0; nj < 4; ++nj)
                bfv[nj] = *(const bf16x8*)&lds[wj + nj * 16 + rsel][kk];
            #pragma unroll
            for (int mi = 0; mi < 4; ++mi)
                #pragma unroll
                for (int nj = 0; nj < 4; ++nj)
                    acc[mi][nj] = __builtin_amdgcn_mfma_f32_16x16x32_bf16(
                        af[mi], bfv[nj], acc[mi][nj], 0, 0, 0);
        }
    }

    float* rsm = rowsum + m * NF;
    #pragma unroll
    for (int j = 0; j < 4; ++j) {
        float v = rs[j];
        v += __shfl_xor(v, 1);
        v += __shfl_xor(v, 2);
        v += __shfl_xor(v, 4);
        v += __shfl_xor(v, 8);
        if ((lane & 15) == 0) atomicAdd(rsm + fr + j * 64, v);
    }

    float* g = gram + (size_t)m * NF * NF;
    const int rowb = (lane >> 4) * 4;
    const int colb = lane & 15;
    #pragma unroll
    for (int mi = 0; mi < 4; ++mi)
        #pragma unroll
        for (int nj = 0; nj < 4; ++nj) {
            const int row = wi + mi * 16 + rowb;
            const int col = wj + nj * 16 + colb;
            #pragma unroll
            for (int r = 0; r < 4; ++r)
                atomicAdd(g + (size_t)(row + r) * NF + col, acc[mi][nj][r]);
        }
}

// ---------------------------------------------------------------------------
// K2: cov formation + Cholesky, LDS-resident packed triangle.
// One block (1024 thr, 16 waves) per matrix. Per panel (width 32):
//   P1: wave0 factors diag (1 shuffle/step) + computes W=inv(Db) + writes
//       W as split-bf16; waves 1..15 prefetch+convert Pan frags to regs.
//   P2: all waves: X = Pan·Wᵀ via 3 MFMAs/tile; X -> Lt (fp32) + Pb (bf16).
//   P3: trailing syrk C -= X·Xᵀ via MFMA, RMW in LDS.
// ---------------------------------------------------------------------------

__device__ __forceinline__ void load_split_frag(const float* Lt, int row, int jb,
                                                int lane, bf16x8& h, bf16x8& l) {
    const int koff = (lane >> 4) * 8;
    const int base = ((row * (row + 1)) >> 1) + jb + koff;
    #pragma unroll
    for (int u = 0; u < 8; ++u) {
        const float f = Lt[base + u];
        const short hh = f2bf(f);
        h[u] = hh;
        l[u] = f2bf(f - bf2f(hh));
    }
}

__device__ __forceinline__ void apply_tile(int tile, bf16x8 ph, bf16x8 pl,
                                           float* Lt, short (*Pb)[40],
                                           const short (*Whs)[40],
                                           const short (*Wls)[40],
                                           int jb, int R0, int lane) {
    const int r0   = (tile >> 1) * 16;
    const int c0   = (tile & 1) * 16;
    const int koff = (lane >> 4) * 8;
    bf16x8 wh = *(const bf16x8*)&Whs[c0 + (lane & 15)][koff];
    bf16x8 wl = *(const bf16x8*)&Wls[c0 + (lane & 15)][koff];
    f32x4 acc = {0.f, 0.f, 0.f, 0.f};
    acc = __builtin_amdgcn_mfma_f32_16x16x32_bf16(ph, wh, acc, 0, 0, 0);
    acc = __builtin_amdgcn_mfma_f32_16x16x32_bf16(pl, wh, acc, 0, 0, 0);
    acc = __builtin_amdgcn_mfma_f32_16x16x32_bf16(ph, wl, acc, 0, 0, 0);
    const int col  = c0 + (lane & 15);
    const int rowb = r0 + (lane >> 4) * 4;
    #pragma unroll
    for (int rg = 0; rg < 4; ++rg) {
        const int rr  = rowb + rg;
        const int row = R0 + rr;
        Lt[((row * (row + 1)) >> 1) + jb + col] = acc[rg];
        Pb[rr][col] = f2bf(acc[rg]);
    }
}

__global__ __launch_bounds__(1024) void k_chol(float* __restrict__ Lg_all,
                                               const float* __restrict__ rowsum,
                                               float* __restrict__ LcT_all,
                                               float* __restrict__ mean_all) {
    const int m = blockIdx.x;
    float* __restrict__ Lg  = Lg_all + (size_t)m * NF * NF;   // aliases gram[m]
    float* __restrict__ LcT = (m < BATCH) ? (LcT_all + (size_t)m * NF * NF) : nullptr;

    __shared__ float Lt[32896];     // packed lower triangle (131584 B)
    __shared__ float Sm[NF];
    __shared__ float Db[32][36];    // factored diag block rows (f32x4-aligned)
    __shared__ short Whs[32][40];   // W = inv(Db), bf16 hi, row-major, padded
    __shared__ short Wls[32][40];   // W lo residual
    __shared__ short Pb[224][40];   // solved panel, bf16, 80B rows

    const int t    = threadIdx.x;
    const int lane = t & 63;
    const int wv   = t >> 6;

    if (t < NF) {
        float s = rowsum[m * NF + t];
        Sm[t] = s;
        mean_all[m * NF + t] = s * (1.f / (float)LSP);
    }
    __syncthreads();

    // cov = (G - S·Sᵀ/L)/(L-1) + eps·I, built straight into packed LDS
    const float invLn  = 1.f / (float)LSP;
    const float invLm1 = 1.f / (float)(LSP - 1);
    for (int idx = t; idx < NF * NF; idx += 1024) {
        const int r = idx >> 8, c = idx & 255;
        if (c <= r) {
            float v = (Lg[idx] - Sm[r] * Sm[c] * invLn) * invLm1;
            if (c == r) v += EPS_J;
            Lt[((r * (r + 1)) >> 1) + c] = v;
        }
    }
    __syncthreads();

    for (int jb = 0; jb < NF; jb += 32) {
        const int R0 = jb + 32;
        const int R  = NF - R0;          // rows below the diag block (224..0)
        const int nT = (R >> 4) * 2;     // apply tiles (16 rows x 16 cols)

        // ------------------ P1 ------------------
        bf16x8 ph0, pl0, ph1, pl1;
        int tw0 = -1, tw1 = -1;
        if (wv > 0) {
            // prefetch + split-convert Pan fragments (values final since the
            // end-of-previous-panel barrier) while wave 0 factors.
            const int tb = wv - 1;
            if (tb < nT) {
                tw0 = tb;
                load_split_frag(Lt, R0 + (tb >> 1) * 16 + (lane & 15), jb, lane, ph0, pl0);
            }
            if (tb + 15 < nT) {
                tw1 = tb + 15;
                load_split_frag(Lt, R0 + ((tb + 15) >> 1) * 16 + (lane & 15), jb, lane, ph1, pl1);
            }
        } else if (t < 32) {
            // --- A: factor 32x32 diag block; lane r holds row r ---
            const int r = t;
            const int rbase = (((jb + r) * (jb + r + 1)) >> 1) + jb;
            float a[32];
            #pragma unroll
            for (int c = 0; c < 32; ++c)
                a[c] = (c <= r) ? Lt[rbase + c] : 0.f;
            #pragma unroll
            for (int j = 0; j < 32; ++j) {
                const float ajv = a[j];                 // unscaled column j
                const float d   = __shfl(ajv, j);       // pivot (uniform)
                const float rd  = __builtin_amdgcn_rcpf(d);
                const float rs  = __builtin_amdgcn_rsqf(d);
                const float sc  = ajv * rd;             // A[r][j]/d
                #pragma unroll
                for (int c = j + 1; c < 32; ++c)
                    a[c] -= sc * __shfl(ajv, c);        // -= A[r][j]·A[c][j]/d
                a[j] = ajv * rs;                        // final L[r][j] (lane j: sqrt(d))
            }
            // write L diag rows back + publish Db rows (upper junk unread)
            #pragma unroll
            for (int c = 0; c < 32; ++c)
                if (c <= r) Lt[rbase + c] = a[c];
            #pragma unroll
            for (int c4 = 0; c4 < 8; ++c4) {
                f32x4 v = { a[c4 * 4], a[c4 * 4 + 1], a[c4 * 4 + 2], a[c4 * 4 + 3] };
                *(f32x4*)&Db[r][c4 * 4] = v;
            }

            // --- W = inv(Db): lane k solves column k by forward subst. ---
            if (R > 0) {
                const int k = r;
                float wcol[32];
                #pragma unroll
                for (int c = 0; c < 32; ++c) wcol[c] = 0.f;
                #pragma unroll
                for (int c = 0; c < 32; ++c) {
                    float s = (c == k) ? 1.f : 0.f;
                    const int ng = c >> 2;              // groups covering j<=c
                    #pragma unroll
                    for (int g = 0; g <= 7; ++g) {
                        if (g <= ng) {
                            f32x4 dv = *(const f32x4*)&Db[c][g * 4];  // broadcast
                            s -= dv[0] * wcol[g * 4]     + dv[1] * wcol[g * 4 + 1]
                               + dv[2] * wcol[g * 4 + 2] + dv[3] * wcol[g * 4 + 3];
                        }
                    }
                    wcol[c] = s * __builtin_amdgcn_rcpf(Db[c][c]);
                }
                // publish W split-bf16, row-major (row c contiguous in k)
                #pragma unroll
                for (int c = 0; c < 32; ++c) {
                    const float wv_ = wcol[c];
                    const short hh = f2bf(wv_);
                    Whs[c][k] = hh;
                    Wls[c][k] = f2bf(wv_ - bf2f(hh));
                }
            }
        }
        __syncthreads();   // Whs/Wls + diag rows ready; frags in regs

        // ------------------ P2: X = Pan·Wᵀ ------------------
        if (tw0 >= 0) apply_tile(tw0, ph0, pl0, Lt, Pb, Whs, Wls, jb, R0, lane);
        if (tw1 >= 0) apply_tile(tw1, ph1, pl1, Lt, Pb, Whs, Wls, jb, R0, lane);
        __syncthreads();   // X in Lt + Pb ready

        // ------------------ P3: trailing syrk ------------------
        if (R > 0) {
            const int nt  = R >> 4;
            const int ntt = nt * (nt + 1) / 2;
            for (int tt = wv; tt < ntt; tt += 16) {
                int tr = (int)((sqrtf(8.f * (float)tt + 1.f) - 1.f) * 0.5f);
                while ((tr + 1) * (tr + 2) / 2 <= tt) ++tr;
                while (tr * (tr + 1) / 2 > tt) --tr;
                const int tc = tt - tr * (tr + 1) / 2;
                const int r0 = tr * 16, c0 = tc * 16;   // relative to R0
                bf16x8 af  = *(const bf16x8*)&Pb[r0 + (lane & 15)][(lane >> 4) * 8];
                bf16x8 bfv = *(const bf16x8*)&Pb[c0 + (lane & 15)][(lane >> 4) * 8];
                f32x4 accv = {0.f, 0.f, 0.f, 0.f};
                accv = __builtin_amdgcn_mfma_f32_16x16x32_bf16(af, bfv, accv, 0, 0, 0);
                const int col  = R0 + c0 + (lane & 15);
                const int rowb = R0 + r0 + (lane >> 4) * 4;
                if (tr != tc) {
                    #pragma unroll
                    for (int rg = 0; rg < 4; ++rg) {
                        const int row = rowb + rg;
                        Lt[((row * (row + 1)) >> 1) + col] -= accv[rg];
                    }
                } else {
                    #pragma unroll
                    for (int rg = 0; rg < 4; ++rg) {
                        const int row = rowb + rg;
                        if (col <= row)
                            Lt[((row * (row + 1)) >> 1) + col] -= accv[rg];
                    }
                }
            }
        }
        __syncthreads();   // trailing updated before next panel
    }

    // epilogue: one-shot write-out
    if (LcT) {
        // content: LcT[c][r] = L[r][c] (r >= c) — k_solveT reads LcT rows.
        for (int idx = t; idx < NF * NF; idx += 1024) {
            const int cc = idx >> 8, rr = idx & 255;
            if (rr >= cc) LcT[idx] = Lt[((rr * (rr + 1)) >> 1) + cc];
        }
    } else {
        // style: lower triangle back into Lg (= Ls); upper never read.
        for (int idx = t; idx < NF * NF; idx += 1024) {
            const int r = idx >> 8, c = idx & 255;
            if (c <= r) Lg[idx] = Lt[((r * (r + 1)) >> 1) + c];
        }
    }
}

// ---------------------------------------------------------------------------
// K3: solve T·Lc = Ls per row of T (T lower-triangular), write Tbf (bf16)
// and bias[i] = s_mean[i] − Σ_k T[i,k]·c_mean[k]. One wave per (b, i).
// grid 512 x 256 thr (4 waves). Lc read via LcT (contiguous columns).
// ---------------------------------------------------------------------------
__global__ __launch_bounds__(256) void k_solveT(const float* __restrict__ Lg_all,
                                                const float* __restrict__ LcT_all,
                                                const float* __restrict__ mean_all,
                                                short* __restrict__ Tbf,
                                                float* __restrict__ bias) {
    const int lane = threadIdx.x & 63;
    const int wv   = threadIdx.x >> 6;
    const int task = blockIdx.x * 4 + wv;
    const int b    = task >> 8;
    const int i    = task & 255;
    const float* __restrict__ Ls  = Lg_all + (size_t)(BATCH + b) * NF * NF + (size_t)i * NF;
    const float* __restrict__ LcT = LcT_all + (size_t)b * NF * NF;

    __shared__ float vbuf[4][NF];
    float* vb = vbuf[wv];
    for (int k = lane; k < NF; k += 64) vb[k] = 0.f;

    int j = i;
    for (; j >= 1; j -= 2) {
        const float* __restrict__ r0 = LcT + (size_t)j * NF;        // Lc[k][j]
        const float* __restrict__ r1 = r0 - NF;                     // Lc[k][j-1]
        float s0 = 0.f, s1 = 0.f;
        for (int k = j + 1 + lane; k <= i; k += 64) {
            const float tk = vb[k];
            s0 += tk * r0[k];
            s1 += tk * r1[k];
        }
        #pragma unroll
        for (int mm = 32; mm >= 1; mm >>= 1) {
            s0 += __shfl_xor(s0, mm);
            s1 += __shfl_xor(s1, mm);
        }
        if (lane == 0) {
            const float tj  = (Ls[j] - s0) / r0[j];
            const float tjm = (Ls[j - 1] - s1 - tj * r1[j]) / r1[j - 1];
            vb[j]     = tj;
            vb[j - 1] = tjm;
        }
    }
    if (j == 0) {
        const float* __restrict__ r0 = LcT;
        float s0 = 0.f;
        for (int k = 1 + lane; k <= i; k += 64) s0 += vb[k] * r0[k];
        #pragma unroll
        for (int mm = 32; mm >= 1; mm >>= 1) s0 += __shfl_xor(s0, mm);
        if (lane == 0) vb[0] = (Ls[0] - s0) / r0[0];
    }

    // bias[i] = s_mean[i] − Σ T[i,k]·c_mean[k]
    const float* __restrict__ cm  = mean_all + b * NF;
    const float* __restrict__ smn = mean_all + (BATCH + b) * NF;
    float dot = 0.f;
    for (int k = lane; k < NF; k += 64) dot += vb[k] * cm[k];
    #pragma unroll
    for (int mm = 32; mm >= 1; mm >>= 1) dot += __shfl_xor(dot, mm);
    if (lane == 0) bias[b * NF + i] = smn[i] - dot;

    short* __restrict__ Tr = Tbf + (size_t)b * NF * NF + (size_t)i * NF;
    const int k4 = lane * 4;
    short4v o = { f2bf(vb[k4]), f2bf(vb[k4 + 1]), f2bf(vb[k4 + 2]), f2bf(vb[k4 + 3]) };
    *(short4v*)&Tr[k4] = o;
}

// ---------------------------------------------------------------------------
// K4: out = T·xc + bias. bf16 MFMA, tile 256(i) x 64(l), K=256.
// grid (256 l-tiles, 8 batches), 256 thr (4 waves of 64x64).
// ---------------------------------------------------------------------------
__global__ __launch_bounds__(256) void k_out(const float* __restrict__ cont,
                                             const short* __restrict__ Tbf,
                                             const float* __restrict__ bias,
                                             float* __restrict__ out) {
    const int b  = blockIdx.y;
    const int l0 = blockIdx.x * 64;
    const float* __restrict__ X  = cont + (size_t)b * NF * LSP;
    const short* __restrict__ Tb = Tbf + (size_t)b * NF * NF;
    float* __restrict__ O = out + (size_t)b * NF * LSP;

    __shared__ short a_s[256][72];
    __shared__ short b_s[64][72];
    __shared__ float bias_s[NF];

    const int t    = threadIdx.x;
    const int lane = t & 63;
    const int w    = t >> 6;

    bias_s[t] = bias[b * NF + t];

    f32x4 acc[4][4];
    #pragma unroll
    for (int i = 0; i < 4; ++i)
        #pragma unroll
        for (int j = 0; j < 4; ++j) { f32x4 z = {0.f,0.f,0.f,0.f}; acc[i][j] = z; }

    const int kb = (t >> 4) * 4;
    const int lb = (t & 15) * 4;
    const int fr = t >> 4;
    const int fc = (t & 15) * 4;

    float4 xr[4];
    #pragma unroll
    for (int r = 0; r < 4; ++r)
        xr[r] = *(const float4*)(X + (size_t)(kb + r) * LSP + l0 + lb);

    for (int step = 0; step < 4; ++step) {
        const int k0 = step * 64;
        __syncthreads();
        #pragma unroll
        for (int s2 = 0; s2 < 16; ++s2) {
            const int row = fr + s2 * 16;
            *(short4v*)&a_s[row][fc] = *(const short4v*)(Tb + (size_t)row * NF + k0 + fc);
        }
        {
            short4v c0v = { f2bf(xr[0].x), f2bf(xr[1].x), f2bf(xr[2].x), f2bf(xr[3].x) };
            short4v c1v = { f2bf(xr[0].y), f2bf(xr[1].y), f2bf(xr[2].y), f2bf(xr[3].y) };
            short4v c2v = { f2bf(xr[0].z), f2bf(xr[1].z), f2bf(xr[2].z), f2bf(xr[3].z) };
            short4v c3v = { f2bf(xr[0].w), f2bf(xr[1].w), f2bf(xr[2].w), f2bf(xr[3].w) };
            *(short4v*)&b_s[lb + 0][kb] = c0v;
            *(short4v*)&b_s[lb + 1][kb] = c1v;
            *(short4v*)&b_s[lb + 2][kb] = c2v;
            *(short4v*)&b_s[lb + 3][kb] = c3v;
        }
        __syncthreads();
        if (step < 3) {
            const int k0n = k0 + 64;
            #pragma unroll
            for (int r = 0; r < 4; ++r)
                xr[r] = *(const float4*)(X + (size_t)(k0n + kb + r) * LSP + l0 + lb);
        }
        #pragma unroll
        for (int ks = 0; ks < 2; ++ks) {
            const int kk   = ks * 32 + (lane >> 4) * 8;
            const int rsel = lane & 15;
            bf16x8 af[4], bfv[4];
            #pragma unroll
            for (int mi = 0; mi < 4; ++mi)
                af[mi] = *(const bf16x8*)&a_s[w * 64 + mi * 16 + rsel][kk];
            #pragma unroll
            for (int nj = 0; nj < 4; ++nj)
                bfv[nj] = *(const bf16x8*)&b_s[nj * 16 + rsel][kk];
            #pragma unroll
            for (int mi = 0; mi < 4; ++mi)
                #pragma unroll
                for (int nj = 0; nj < 4; ++nj)
                    acc[mi][nj] = __builtin_amdgcn_mfma_f32_16x16x32_bf16(
                        af[mi], bfv[nj], acc[mi][nj], 0, 0, 0);
        }
    }

    #pragma unroll
    for (int mi = 0; mi < 4; ++mi) {
        const int row = w * 64 + mi * 16 + (lane >> 4) * 4;
        #pragma unroll
        for (int nj = 0; nj < 4; ++nj) {
            const int col = l0 + nj * 16 + (lane & 15);
            #pragma unroll
            for (int r = 0; r < 4; ++r)
                O[(size_t)(row + r) * LSP + col] = acc[mi][nj][r] + bias_s[row + r];
        }
    }
}

// ---------------------------------------------------------------------------
extern "C" void kernel_launch(void* const* d_in, const int* in_sizes, int n_in,
                              void* d_out, int out_size, void* d_ws, size_t ws_size,
                              hipStream_t stream) {
    (void)in_sizes; (void)n_in; (void)out_size; (void)ws_size;
    const float* cont = (const float*)d_in[0];
    const float* styl = (const float*)d_in[1];
    float* out = (float*)d_out;

    float* ws       = (float*)d_ws;
    float* gram     = ws;                         // 16*65536 f32 — reused as Lg
    float* rowsum   = gram + 16 * 65536;          // 16*256
    float* mean_all = rowsum + 4096;              // 16*256
    float* bias     = mean_all + 4096;            // 8*256
    float* LcT      = bias + 2048;                // 8*65536 f32 (2 MB)
    short* Tbf      = (short*)(LcT + 8 * 65536);  // 8*65536 bf16 (1 MB)

    // zero gram + rowsum (atomic accumulation targets)
    hipMemsetAsync(gram, 0, (size_t)(16 * 65536 + 4096) * sizeof(float), stream);

    k_cov   <<<dim3(16, 16), 1024, 0, stream>>>(cont, styl, gram, rowsum);
    k_chol  <<<16,           1024, 0, stream>>>(gram, rowsum, LcT, mean_all);
    k_solveT<<<512,          256,  0, stream>>>(gram, LcT, mean_all, Tbf, bias);
    k_out   <<<dim3(256, 8), 256,  0, stream>>>(cont, Tbf, bias, out);
}

// Round 3
// 698.631 us; speedup vs baseline: 1.1895x; 1.0314x over previous
//
#include <hip/hip_runtime.h>

// cWCT: out = Ls·inv(Lc)·(xc − c_mean) + s_mean  =  T·xc + bias
// B=8, N=256, L=16384. fp32 in/out; bf16 MFMA for the big GEMMs.
// Round 5:
//  - k_chol: __launch_bounds__(1024,4) -> VGPR cap 128 (was 64, spilling:
//    WRITE_SIZE showed ~2.4MB of scratch traffic feeding the serial
//    factor path). LDS already limits to 1 block/CU, so no occupancy cost.
//  - k_cov: lower-triangle-only MFMA (gram upper half was never read) and
//    split-K reduction via streaming partial stores + k_reduce kernel
//    instead of 16.7M device-scope fp32 atomicAdds (cross-XCD RMW storm).
//    Falls back to the atomic path if ws_size is too small.

#define BATCH 8
#define NF    256
#define LSP   16384
#define EPS_J 2e-5f

typedef float f32x4  __attribute__((ext_vector_type(4)));
typedef short bf16x8 __attribute__((ext_vector_type(8)));
typedef short short4v __attribute__((ext_vector_type(4)));

__device__ __forceinline__ short f2bf(float f) {
    unsigned u = __float_as_uint(f);
    u = (u + 0x7FFFu + ((u >> 16) & 1u)) >> 16;   // RNE to bf16
    return (short)u;
}
__device__ __forceinline__ float bf2f(short s) {
    return __uint_as_float(((unsigned)(unsigned short)s) << 16);
}

// lower-triangular wave-tile map: w in [0,10) -> (ti,tj), ti>=tj
__device__ __forceinline__ void tri_map(int w, int& ti, int& tj) {
    ti = (w >= 6) ? 3 : ((w >= 3) ? 2 : ((w >= 1) ? 1 : 0));
    tj = w - ti * (ti + 1) / 2;
}

// ---------------------------------------------------------------------------
// K1: batched syrk  gram[m] += A·Aᵀ (bf16 MFMA, split-K) + fp32 row sums.
// grid (splitk=16, m=16), 1024 threads. Lower wave-tiles only (10 of 16).
// use_part: write per-split partials (no atomics); else atomicAdd fallback.
// ---------------------------------------------------------------------------
__global__ __launch_bounds__(1024, 4) void k_cov(const float* __restrict__ cont,
                                                 const float* __restrict__ styl,
                                                 float* __restrict__ gram,
                                                 float* __restrict__ rowsum,
                                                 float* __restrict__ part,
                                                 int use_part) {
    const int kc = blockIdx.x;
    const int m  = blockIdx.y;
    const float* __restrict__ src = (m < BATCH)
        ? cont + (size_t)m * NF * LSP
        : styl + (size_t)(m - BATCH) * NF * LSP;

    __shared__ short lds[256][72];

    const int t    = threadIdx.x;
    const int lane = t & 63;
    const int w    = t >> 6;
    int ti = 0, tj = 0;
    tri_map(w < 10 ? w : 0, ti, tj);
    const int wi = ti * 64;
    const int wj = tj * 64;
    const int fr = t >> 4;
    const int fc = (t & 15) * 4;

    f32x4 acc[4][4];
    #pragma unroll
    for (int i = 0; i < 4; ++i)
        #pragma unroll
        for (int j = 0; j < 4; ++j) { f32x4 z = {0.f,0.f,0.f,0.f}; acc[i][j] = z; }

    float rs[4] = {0.f, 0.f, 0.f, 0.f};

    const size_t kbase = (size_t)kc * 1024;
    float4 pre[4];
    #pragma unroll
    for (int j = 0; j < 4; ++j)
        pre[j] = *(const float4*)(src + (size_t)(fr + j * 64) * LSP + kbase + fc);

    for (int step = 0; step < 16; ++step) {
        __syncthreads();
        #pragma unroll
        for (int j = 0; j < 4; ++j) {
            float4 v = pre[j];
            rs[j] += v.x + v.y + v.z + v.w;
            short4v b4 = { f2bf(v.x), f2bf(v.y), f2bf(v.z), f2bf(v.w) };
            *(short4v*)&lds[fr + j * 64][fc] = b4;
        }
        __syncthreads();
        if (step < 15) {
            const size_t k0n = kbase + (size_t)(step + 1) * 64;
            #pragma unroll
            for (int j = 0; j < 4; ++j)
                pre[j] = *(const float4*)(src + (size_t)(fr + j * 64) * LSP + k0n + fc);
        }
        if (w < 10) {
            #pragma unroll
            for (int ks = 0; ks < 2; ++ks) {
                const int kk   = ks * 32 + (lane >> 4) * 8;
                const int rsel = lane & 15;
                bf16x8 af[4], bfv[4];
                #pragma unroll
                for (int mi = 0; mi < 4; ++mi)
                    af[mi] = *(const bf16x8*)&lds[wi + mi * 16 + rsel][kk];
                #pragma unroll
                for (int nj = 0; nj < 4; ++nj)
                    bfv[nj] = *(const bf16x8*)&lds[wj + nj * 16 + rsel][kk];
                #pragma unroll
                for (int mi = 0; mi < 4; ++mi)
                    #pragma unroll
                    for (int nj = 0; nj < 4; ++nj)
                        acc[mi][nj] = __builtin_amdgcn_mfma_f32_16x16x32_bf16(
                            af[mi], bfv[nj], acc[mi][nj], 0, 0, 0);
            }
        }
    }

    float* rsm = rowsum + m * NF;
    #pragma unroll
    for (int j = 0; j < 4; ++j) {
        float v = rs[j];
        v += __shfl_xor(v, 1);
        v += __shfl_xor(v, 2);
        v += __shfl_xor(v, 4);
        v += __shfl_xor(v, 8);
        if ((lane & 15) == 0) atomicAdd(rsm + fr + j * 64, v);
    }

    if (w >= 10) return;

    const int rowb = (lane >> 4) * 4;
    const int colb = lane & 15;
    if (use_part) {
        // streaming store of this split's tile: part[(m*16+kc)*10 + w][64*64]
        float* __restrict__ pt = part + (((size_t)m * 16 + kc) * 10 + w) * 4096;
        #pragma unroll
        for (int mi = 0; mi < 4; ++mi)
            #pragma unroll
            for (int nj = 0; nj < 4; ++nj) {
                const int rl = mi * 16 + rowb;
                const int cl = nj * 16 + colb;
                #pragma unroll
                for (int r = 0; r < 4; ++r)
                    pt[(size_t)(rl + r) * 64 + cl] = acc[mi][nj][r];
            }
    } else {
        float* g = gram + (size_t)m * NF * NF;
        #pragma unroll
        for (int mi = 0; mi < 4; ++mi)
            #pragma unroll
            for (int nj = 0; nj < 4; ++nj) {
                const int row = wi + mi * 16 + rowb;
                const int col = wj + nj * 16 + colb;
                #pragma unroll
                for (int r = 0; r < 4; ++r)
                    atomicAdd(g + (size_t)(row + r) * NF + col, acc[mi][nj][r]);
            }
    }
}

// ---------------------------------------------------------------------------
// K1b: reduce the 16 split-K partials into gram (lower tiles only).
// grid 160 (= 16 m × 10 tiles), 256 threads.
// ---------------------------------------------------------------------------
__global__ __launch_bounds__(256) void k_reduce(const float* __restrict__ part,
                                                float* __restrict__ gram) {
    const int m  = blockIdx.x / 10;
    const int tt = blockIdx.x % 10;
    int ti, tj;
    tri_map(tt, ti, tj);
    const float* __restrict__ base = part + ((size_t)m * 16 * 10 + tt) * 4096;
    float* __restrict__ g = gram + (size_t)m * NF * NF;
    for (int e = threadIdx.x; e < 4096; e += 256) {
        float s = 0.f;
        #pragma unroll
        for (int sp = 0; sp < 16; ++sp)
            s += base[(size_t)sp * 10 * 4096 + e];
        g[(size_t)(ti * 64 + (e >> 6)) * NF + tj * 64 + (e & 63)] = s;
    }
}

// ---------------------------------------------------------------------------
// K2: cov formation + Cholesky, LDS-resident packed triangle.
// One block (1024 thr, 16 waves) per matrix. Per panel (width 32):
//   P1: wave0 factors diag (1 shuffle/step) + computes W=inv(Db) + writes
//       W as split-bf16; waves 1..15 prefetch+convert Pan frags to regs.
//   P2: all waves: X = Pan·Wᵀ via 3 MFMAs/tile; X -> Lt (fp32) + Pb (bf16).
//   P3: trailing syrk C -= X·Xᵀ via MFMA, RMW in LDS.
// launch_bounds(1024,4): allow 128 VGPRs (round-4 spilled at 64).
// ---------------------------------------------------------------------------

__device__ __forceinline__ void load_split_frag(const float* Lt, int row, int jb,
                                                int lane, bf16x8& h, bf16x8& l) {
    const int koff = (lane >> 4) * 8;
    const int base = ((row * (row + 1)) >> 1) + jb + koff;
    #pragma unroll
    for (int u = 0; u < 8; ++u) {
        const float f = Lt[base + u];
        const short hh = f2bf(f);
        h[u] = hh;
        l[u] = f2bf(f - bf2f(hh));
    }
}

__device__ __forceinline__ void apply_tile(int tile, bf16x8 ph, bf16x8 pl,
                                           float* Lt, short (*Pb)[40],
                                           const short (*Whs)[40],
                                           const short (*Wls)[40],
                                           int jb, int R0, int lane) {
    const int r0   = (tile >> 1) * 16;
    const int c0   = (tile & 1) * 16;
    const int koff = (lane >> 4) * 8;
    bf16x8 wh = *(const bf16x8*)&Whs[c0 + (lane & 15)][koff];
    bf16x8 wl = *(const bf16x8*)&Wls[c0 + (lane & 15)][koff];
    f32x4 acc = {0.f, 0.f, 0.f, 0.f};
    acc = __builtin_amdgcn_mfma_f32_16x16x32_bf16(ph, wh, acc, 0, 0, 0);
    acc = __builtin_amdgcn_mfma_f32_16x16x32_bf16(pl, wh, acc, 0, 0, 0);
    acc = __builtin_amdgcn_mfma_f32_16x16x32_bf16(ph, wl, acc, 0, 0, 0);
    const int col  = c0 + (lane & 15);
    const int rowb = r0 + (lane >> 4) * 4;
    #pragma unroll
    for (int rg = 0; rg < 4; ++rg) {
        const int rr  = rowb + rg;
        const int row = R0 + rr;
        Lt[((row * (row + 1)) >> 1) + jb + col] = acc[rg];
        Pb[rr][col] = f2bf(acc[rg]);
    }
}

__global__ __launch_bounds__(1024, 4) void k_chol(float* __restrict__ Lg_all,
                                                  const float* __restrict__ rowsum,
                                                  float* __restrict__ LcT_all,
                                                  float* __restrict__ mean_all) {
    const int m = blockIdx.x;
    float* __restrict__ Lg  = Lg_all + (size_t)m * NF * NF;   // aliases gram[m]
    float* __restrict__ LcT = (m < BATCH) ? (LcT_all + (size_t)m * NF * NF) : nullptr;

    __shared__ float Lt[32896];     // packed lower triangle (131584 B)
    __shared__ float Sm[NF];
    __shared__ float Db[32][36];    // factored diag block rows (f32x4-aligned)
    __shared__ short Whs[32][40];   // W = inv(Db), bf16 hi, row-major, padded
    __shared__ short Wls[32][40];   // W lo residual
    __shared__ short Pb[224][40];   // solved panel, bf16, 80B rows

    const int t    = threadIdx.x;
    const int lane = t & 63;
    const int wv   = t >> 6;

    if (t < NF) {
        float s = rowsum[m * NF + t];
        Sm[t] = s;
        mean_all[m * NF + t] = s * (1.f / (float)LSP);
    }
    __syncthreads();

    // cov = (G - S·Sᵀ/L)/(L-1) + eps·I, built straight into packed LDS
    const float invLn  = 1.f / (float)LSP;
    const float invLm1 = 1.f / (float)(LSP - 1);
    for (int idx = t; idx < NF * NF; idx += 1024) {
        const int r = idx >> 8, c = idx & 255;
        if (c <= r) {
            float v = (Lg[idx] - Sm[r] * Sm[c] * invLn) * invLm1;
            if (c == r) v += EPS_J;
            Lt[((r * (r + 1)) >> 1) + c] = v;
        }
    }
    __syncthreads();

    for (int jb = 0; jb < NF; jb += 32) {
        const int R0 = jb + 32;
        const int R  = NF - R0;          // rows below the diag block (224..0)
        const int nT = (R >> 4) * 2;     // apply tiles (16 rows x 16 cols)

        // ------------------ P1 ------------------
        bf16x8 ph0, pl0, ph1, pl1;
        int tw0 = -1, tw1 = -1;
        if (wv > 0) {
            // prefetch + split-convert Pan fragments (values final since the
            // end-of-previous-panel barrier) while wave 0 factors.
            const int tb = wv - 1;
            if (tb < nT) {
                tw0 = tb;
                load_split_frag(Lt, R0 + (tb >> 1) * 16 + (lane & 15), jb, lane, ph0, pl0);
            }
            if (tb + 15 < nT) {
                tw1 = tb + 15;
                load_split_frag(Lt, R0 + ((tb + 15) >> 1) * 16 + (lane & 15), jb, lane, ph1, pl1);
            }
        } else if (t < 32) {
            // --- A: factor 32x32 diag block; lane r holds row r ---
            const int r = t;
            const int rbase = (((jb + r) * (jb + r + 1)) >> 1) + jb;
            float a[32];
            #pragma unroll
            for (int c = 0; c < 32; ++c)
                a[c] = (c <= r) ? Lt[rbase + c] : 0.f;
            #pragma unroll
            for (int j = 0; j < 32; ++j) {
                const float ajv = a[j];                 // unscaled column j
                const float d   = __shfl(ajv, j);       // pivot (uniform)
                const float rd  = __builtin_amdgcn_rcpf(d);
                const float rs  = __builtin_amdgcn_rsqf(d);
                const float sc  = ajv * rd;             // A[r][j]/d
                #pragma unroll
                for (int c = j + 1; c < 32; ++c)
                    a[c] -= sc * __shfl(ajv, c);        // -= A[r][j]·A[c][j]/d
                a[j] = ajv * rs;                        // final L[r][j] (lane j: sqrt(d))
            }
            // write L diag rows back + publish Db rows (upper junk unread)
            #pragma unroll
            for (int c = 0; c < 32; ++c)
                if (c <= r) Lt[rbase + c] = a[c];
            #pragma unroll
            for (int c4 = 0; c4 < 8; ++c4) {
                f32x4 v = { a[c4 * 4], a[c4 * 4 + 1], a[c4 * 4 + 2], a[c4 * 4 + 3] };
                *(f32x4*)&Db[r][c4 * 4] = v;
            }

            // --- W = inv(Db): lane k solves column k by forward subst. ---
            if (R > 0) {
                const int k = r;
                float wcol[32];
                #pragma unroll
                for (int c = 0; c < 32; ++c) wcol[c] = 0.f;
                #pragma unroll
                for (int c = 0; c < 32; ++c) {
                    float s = (c == k) ? 1.f : 0.f;
                    const int ng = c >> 2;              // groups covering j<=c
                    #pragma unroll
                    for (int g = 0; g <= 7; ++g) {
                        if (g <= ng) {
                            f32x4 dv = *(const f32x4*)&Db[c][g * 4];  // broadcast
                            s -= dv[0] * wcol[g * 4]     + dv[1] * wcol[g * 4 + 1]
                               + dv[2] * wcol[g * 4 + 2] + dv[3] * wcol[g * 4 + 3];
                        }
                    }
                    wcol[c] = s * __builtin_amdgcn_rcpf(Db[c][c]);
                }
                // publish W split-bf16, row-major (row c contiguous in k)
                #pragma unroll
                for (int c = 0; c < 32; ++c) {
                    const float wv_ = wcol[c];
                    const short hh = f2bf(wv_);
                    Whs[c][k] = hh;
                    Wls[c][k] = f2bf(wv_ - bf2f(hh));
                }
            }
        }
        __syncthreads();   // Whs/Wls + diag rows ready; frags in regs

        // ------------------ P2: X = Pan·Wᵀ ------------------
        if (tw0 >= 0) apply_tile(tw0, ph0, pl0, Lt, Pb, Whs, Wls, jb, R0, lane);
        if (tw1 >= 0) apply_tile(tw1, ph1, pl1, Lt, Pb, Whs, Wls, jb, R0, lane);
        __syncthreads();   // X in Lt + Pb ready

        // ------------------ P3: trailing syrk ------------------
        if (R > 0) {
            const int nt  = R >> 4;
            const int ntt = nt * (nt + 1) / 2;
            for (int tt = wv; tt < ntt; tt += 16) {
                int tr = (int)((sqrtf(8.f * (float)tt + 1.f) - 1.f) * 0.5f);
                while ((tr + 1) * (tr + 2) / 2 <= tt) ++tr;
                while (tr * (tr + 1) / 2 > tt) --tr;
                const int tc = tt - tr * (tr + 1) / 2;
                const int r0 = tr * 16, c0 = tc * 16;   // relative to R0
                bf16x8 af  = *(const bf16x8*)&Pb[r0 + (lane & 15)][(lane >> 4) * 8];
                bf16x8 bfv = *(const bf16x8*)&Pb[c0 + (lane & 15)][(lane >> 4) * 8];
                f32x4 accv = {0.f, 0.f, 0.f, 0.f};
                accv = __builtin_amdgcn_mfma_f32_16x16x32_bf16(af, bfv, accv, 0, 0, 0);
                const int col  = R0 + c0 + (lane & 15);
                const int rowb = R0 + r0 + (lane >> 4) * 4;
                if (tr != tc) {
                    #pragma unroll
                    for (int rg = 0; rg < 4; ++rg) {
                        const int row = rowb + rg;
                        Lt[((row * (row + 1)) >> 1) + col] -= accv[rg];
                    }
                } else {
                    #pragma unroll
                    for (int rg = 0; rg < 4; ++rg) {
                        const int row = rowb + rg;
                        if (col <= row)
                            Lt[((row * (row + 1)) >> 1) + col] -= accv[rg];
                    }
                }
            }
        }
        __syncthreads();   // trailing updated before next panel
    }

    // epilogue: one-shot write-out
    if (LcT) {
        // content: LcT[c][r] = L[r][c] (r >= c) — k_solveT reads LcT rows.
        for (int idx = t; idx < NF * NF; idx += 1024) {
            const int cc = idx >> 8, rr = idx & 255;
            if (rr >= cc) LcT[idx] = Lt[((rr * (rr + 1)) >> 1) + cc];
        }
    } else {
        // style: lower triangle back into Lg (= Ls); upper never read.
        for (int idx = t; idx < NF * NF; idx += 1024) {
            const int r = idx >> 8, c = idx & 255;
            if (c <= r) Lg[idx] = Lt[((r * (r + 1)) >> 1) + c];
        }
    }
}

// ---------------------------------------------------------------------------
// K3: solve T·Lc = Ls per row of T (T lower-triangular), write Tbf (bf16)
// and bias[i] = s_mean[i] − Σ_k T[i,k]·c_mean[k]. One wave per (b, i).
// grid 512 x 256 thr (4 waves). Lc read via LcT (contiguous columns).
// ---------------------------------------------------------------------------
__global__ __launch_bounds__(256) void k_solveT(const float* __restrict__ Lg_all,
                                                const float* __restrict__ LcT_all,
                                                const float* __restrict__ mean_all,
                                                short* __restrict__ Tbf,
                                                float* __restrict__ bias) {
    const int lane = threadIdx.x & 63;
    const int wv   = threadIdx.x >> 6;
    const int task = blockIdx.x * 4 + wv;
    const int b    = task >> 8;
    const int i    = task & 255;
    const float* __restrict__ Ls  = Lg_all + (size_t)(BATCH + b) * NF * NF + (size_t)i * NF;
    const float* __restrict__ LcT = LcT_all + (size_t)b * NF * NF;

    __shared__ float vbuf[4][NF];
    float* vb = vbuf[wv];
    for (int k = lane; k < NF; k += 64) vb[k] = 0.f;

    int j = i;
    for (; j >= 1; j -= 2) {
        const float* __restrict__ r0 = LcT + (size_t)j * NF;        // Lc[k][j]
        const float* __restrict__ r1 = r0 - NF;                     // Lc[k][j-1]
        float s0 = 0.f, s1 = 0.f;
        for (int k = j + 1 + lane; k <= i; k += 64) {
            const float tk = vb[k];
            s0 += tk * r0[k];
            s1 += tk * r1[k];
        }
        #pragma unroll
        for (int mm = 32; mm >= 1; mm >>= 1) {
            s0 += __shfl_xor(s0, mm);
            s1 += __shfl_xor(s1, mm);
        }
        if (lane == 0) {
            const float tj  = (Ls[j] - s0) / r0[j];
            const float tjm = (Ls[j - 1] - s1 - tj * r1[j]) / r1[j - 1];
            vb[j]     = tj;
            vb[j - 1] = tjm;
        }
    }
    if (j == 0) {
        const float* __restrict__ r0 = LcT;
        float s0 = 0.f;
        for (int k = 1 + lane; k <= i; k += 64) s0 += vb[k] * r0[k];
        #pragma unroll
        for (int mm = 32; mm >= 1; mm >>= 1) s0 += __shfl_xor(s0, mm);
        if (lane == 0) vb[0] = (Ls[0] - s0) / r0[0];
    }

    // bias[i] = s_mean[i] − Σ T[i,k]·c_mean[k]
    const float* __restrict__ cm  = mean_all + b * NF;
    const float* __restrict__ smn = mean_all + (BATCH + b) * NF;
    float dot = 0.f;
    for (int k = lane; k < NF; k += 64) dot += vb[k] * cm[k];
    #pragma unroll
    for (int mm = 32; mm >= 1; mm >>= 1) dot += __shfl_xor(dot, mm);
    if (lane == 0) bias[b * NF + i] = smn[i] - dot;

    short* __restrict__ Tr = Tbf + (size_t)b * NF * NF + (size_t)i * NF;
    const int k4 = lane * 4;
    short4v o = { f2bf(vb[k4]), f2bf(vb[k4 + 1]), f2bf(vb[k4 + 2]), f2bf(vb[k4 + 3]) };
    *(short4v*)&Tr[k4] = o;
}

// ---------------------------------------------------------------------------
// K4: out = T·xc + bias. bf16 MFMA, tile 256(i) x 64(l), K=256.
// grid (256 l-tiles, 8 batches), 256 thr (4 waves of 64x64).
// ---------------------------------------------------------------------------
__global__ __launch_bounds__(256) void k_out(const float* __restrict__ cont,
                                             const short* __restrict__ Tbf,
                                             const float* __restrict__ bias,
                                             float* __restrict__ out) {
    const int b  = blockIdx.y;
    const int l0 = blockIdx.x * 64;
    const float* __restrict__ X  = cont + (size_t)b * NF * LSP;
    const short* __restrict__ Tb = Tbf + (size_t)b * NF * NF;
    float* __restrict__ O = out + (size_t)b * NF * LSP;

    __shared__ short a_s[256][72];
    __shared__ short b_s[64][72];
    __shared__ float bias_s[NF];

    const int t    = threadIdx.x;
    const int lane = t & 63;
    const int w    = t >> 6;

    bias_s[t] = bias[b * NF + t];

    f32x4 acc[4][4];
    #pragma unroll
    for (int i = 0; i < 4; ++i)
        #pragma unroll
        for (int j = 0; j < 4; ++j) { f32x4 z = {0.f,0.f,0.f,0.f}; acc[i][j] = z; }

    const int kb = (t >> 4) * 4;
    const int lb = (t & 15) * 4;
    const int fr = t >> 4;
    const int fc = (t & 15) * 4;

    float4 xr[4];
    #pragma unroll
    for (int r = 0; r < 4; ++r)
        xr[r] = *(const float4*)(X + (size_t)(kb + r) * LSP + l0 + lb);

    for (int step = 0; step < 4; ++step) {
        const int k0 = step * 64;
        __syncthreads();
        #pragma unroll
        for (int s2 = 0; s2 < 16; ++s2) {
            const int row = fr + s2 * 16;
            *(short4v*)&a_s[row][fc] = *(const short4v*)(Tb + (size_t)row * NF + k0 + fc);
        }
        {
            short4v c0v = { f2bf(xr[0].x), f2bf(xr[1].x), f2bf(xr[2].x), f2bf(xr[3].x) };
            short4v c1v = { f2bf(xr[0].y), f2bf(xr[1].y), f2bf(xr[2].y), f2bf(xr[3].y) };
            short4v c2v = { f2bf(xr[0].z), f2bf(xr[1].z), f2bf(xr[2].z), f2bf(xr[3].z) };
            short4v c3v = { f2bf(xr[0].w), f2bf(xr[1].w), f2bf(xr[2].w), f2bf(xr[3].w) };
            *(short4v*)&b_s[lb + 0][kb] = c0v;
            *(short4v*)&b_s[lb + 1][kb] = c1v;
            *(short4v*)&b_s[lb + 2][kb] = c2v;
            *(short4v*)&b_s[lb + 3][kb] = c3v;
        }
        __syncthreads();
        if (step < 3) {
            const int k0n = k0 + 64;
            #pragma unroll
            for (int r = 0; r < 4; ++r)
                xr[r] = *(const float4*)(X + (size_t)(k0n + kb + r) * LSP + l0 + lb);
        }
        #pragma unroll
        for (int ks = 0; ks < 2; ++ks) {
            const int kk   = ks * 32 + (lane >> 4) * 8;
            const int rsel = lane & 15;
            bf16x8 af[4], bfv[4];
            #pragma unroll
            for (int mi = 0; mi < 4; ++mi)
                af[mi] = *(const bf16x8*)&a_s[w * 64 + mi * 16 + rsel][kk];
            #pragma unroll
            for (int nj = 0; nj < 4; ++nj)
                bfv[nj] = *(const bf16x8*)&b_s[nj * 16 + rsel][kk];
            #pragma unroll
            for (int mi = 0; mi < 4; ++mi)
                #pragma unroll
                for (int nj = 0; nj < 4; ++nj)
                    acc[mi][nj] = __builtin_amdgcn_mfma_f32_16x16x32_bf16(
                        af[mi], bfv[nj], acc[mi][nj], 0, 0, 0);
        }
    }

    #pragma unroll
    for (int mi = 0; mi < 4; ++mi) {
        const int row = w * 64 + mi * 16 + (lane >> 4) * 4;
        #pragma unroll
        for (int nj = 0; nj < 4; ++nj) {
            const int col = l0 + nj * 16 + (lane & 15);
            #pragma unroll
            for (int r = 0; r < 4; ++r)
                O[(size_t)(row + r) * LSP + col] = acc[mi][nj][r] + bias_s[row + r];
        }
    }
}

// ---------------------------------------------------------------------------
extern "C" void kernel_launch(void* const* d_in, const int* in_sizes, int n_in,
                              void* d_out, int out_size, void* d_ws, size_t ws_size,
                              hipStream_t stream) {
    (void)in_sizes; (void)n_in; (void)out_size;
    const float* cont = (const float*)d_in[0];
    const float* styl = (const float*)d_in[1];
    float* out = (float*)d_out;

    float* ws       = (float*)d_ws;
    float* gram     = ws;                         // 16*65536 f32 — reused as Lg
    float* rowsum   = gram + 16 * 65536;          // 16*256
    float* mean_all = rowsum + 4096;              // 16*256
    float* bias     = mean_all + 4096;            // 8*256
    float* LcT      = bias + 2048;                // 8*65536 f32 (2 MB)
    short* Tbf      = (short*)(LcT + 8 * 65536);  // 8*65536 bf16 (1 MB)
    float* part     = (float*)(Tbf + 8 * 65536);  // 16*16*10*4096 f32 (41.9 MB)

    const size_t need = ((size_t)((char*)(part + (size_t)16 * 16 * 10 * 4096)
                                  - (char*)ws));
    const int use_part = (ws_size >= need) ? 1 : 0;

    if (use_part) {
        hipMemsetAsync(rowsum, 0, (size_t)4096 * sizeof(float), stream);
    } else {
        hipMemsetAsync(gram, 0, (size_t)(16 * 65536 + 4096) * sizeof(float), stream);
    }

    k_cov   <<<dim3(16, 16), 1024, 0, stream>>>(cont, styl, gram, rowsum, part, use_part);
    if (use_part)
        k_reduce<<<160, 256, 0, stream>>>(part, gram);
    k_chol  <<<16,           1024, 0, stream>>>(gram, rowsum, LcT, mean_all);
    k_solveT<<<512,          256,  0, stream>>>(gram, LcT, mean_all, Tbf, bias);
    k_out   <<<dim3(256, 8), 256,  0, stream>>>(cont, Tbf, bias, out);
}

// Round 4
// 622.805 us; speedup vs baseline: 1.3344x; 1.1217x over previous
//
#include <hip/hip_runtime.h>

// cWCT: out = Ls·inv(Lc)·(xc − c_mean) + s_mean  =  T·xc + bias
// B=8, N=256, L=16384. fp32 in/out; bf16 MFMA for the big GEMMs.
// Round 6: k_chol serial-path overlap.
//  - W=inv(Db) computed entirely in registers via v_readlane (no LDS in the
//    dependence chain); factor shuffles also via readlane.
//  - 2 barriers/panel: [all waves: apply X=Pan·W^T, one 16-row stripe per
//    wave] | [wave0: syrk next-diag tiles + factor+inv next diag  ||
//    waves1-15: remaining trailing syrk].  Wave0's serial factor now hides
//    under the parallel syrk instead of serializing the block.
//  - k_reduce emits packed covariance (stats+eps folded), k_chol prologue
//    becomes a coalesced float4 copy.

#define BATCH 8
#define NF    256
#define LSP   16384
#define EPS_J 2e-5f

typedef float f32x4  __attribute__((ext_vector_type(4)));
typedef short bf16x8 __attribute__((ext_vector_type(8)));
typedef short short4v __attribute__((ext_vector_type(4)));

__device__ __forceinline__ short f2bf(float f) {
    unsigned u = __float_as_uint(f);
    u = (u + 0x7FFFu + ((u >> 16) & 1u)) >> 16;   // RNE to bf16
    return (short)u;
}
__device__ __forceinline__ float bf2f(short s) {
    return __uint_as_float(((unsigned)(unsigned short)s) << 16);
}
__device__ __forceinline__ float rlane(float v, int l) {
    return __int_as_float(__builtin_amdgcn_readlane(__float_as_int(v), l));
}

// lower-triangular wave-tile map: w in [0,10) -> (ti,tj), ti>=tj
__device__ __forceinline__ void tri_map(int w, int& ti, int& tj) {
    ti = (w >= 6) ? 3 : ((w >= 3) ? 2 : ((w >= 1) ? 1 : 0));
    tj = w - ti * (ti + 1) / 2;
}

// ---------------------------------------------------------------------------
// K1: batched syrk  gram[m] += A·Aᵀ (bf16 MFMA, split-K) + fp32 row sums.
// grid (splitk=16, m=16), 1024 threads. Lower wave-tiles only (10 of 16).
// use_part: write per-split partials (no atomics); else atomicAdd fallback.
// ---------------------------------------------------------------------------
__global__ __launch_bounds__(1024, 4) void k_cov(const float* __restrict__ cont,
                                                 const float* __restrict__ styl,
                                                 float* __restrict__ gram,
                                                 float* __restrict__ rowsum,
                                                 float* __restrict__ part,
                                                 int use_part) {
    const int kc = blockIdx.x;
    const int m  = blockIdx.y;
    const float* __restrict__ src = (m < BATCH)
        ? cont + (size_t)m * NF * LSP
        : styl + (size_t)(m - BATCH) * NF * LSP;

    __shared__ short lds[256][72];

    const int t    = threadIdx.x;
    const int lane = t & 63;
    const int w    = t >> 6;
    int ti = 0, tj = 0;
    tri_map(w < 10 ? w : 0, ti, tj);
    const int wi = ti * 64;
    const int wj = tj * 64;
    const int fr = t >> 4;
    const int fc = (t & 15) * 4;

    f32x4 acc[4][4];
    #pragma unroll
    for (int i = 0; i < 4; ++i)
        #pragma unroll
        for (int j = 0; j < 4; ++j) { f32x4 z = {0.f,0.f,0.f,0.f}; acc[i][j] = z; }

    float rs[4] = {0.f, 0.f, 0.f, 0.f};

    const size_t kbase = (size_t)kc * 1024;
    float4 pre[4];
    #pragma unroll
    for (int j = 0; j < 4; ++j)
        pre[j] = *(const float4*)(src + (size_t)(fr + j * 64) * LSP + kbase + fc);

    for (int step = 0; step < 16; ++step) {
        __syncthreads();
        #pragma unroll
        for (int j = 0; j < 4; ++j) {
            float4 v = pre[j];
            rs[j] += v.x + v.y + v.z + v.w;
            short4v b4 = { f2bf(v.x), f2bf(v.y), f2bf(v.z), f2bf(v.w) };
            *(short4v*)&lds[fr + j * 64][fc] = b4;
        }
        __syncthreads();
        if (step < 15) {
            const size_t k0n = kbase + (size_t)(step + 1) * 64;
            #pragma unroll
            for (int j = 0; j < 4; ++j)
                pre[j] = *(const float4*)(src + (size_t)(fr + j * 64) * LSP + k0n + fc);
        }
        if (w < 10) {
            #pragma unroll
            for (int ks = 0; ks < 2; ++ks) {
                const int kk   = ks * 32 + (lane >> 4) * 8;
                const int rsel = lane & 15;
                bf16x8 af[4], bfv[4];
                #pragma unroll
                for (int mi = 0; mi < 4; ++mi)
                    af[mi] = *(const bf16x8*)&lds[wi + mi * 16 + rsel][kk];
                #pragma unroll
                for (int nj = 0; nj < 4; ++nj)
                    bfv[nj] = *(const bf16x8*)&lds[wj + nj * 16 + rsel][kk];
                #pragma unroll
                for (int mi = 0; mi < 4; ++mi)
                    #pragma unroll
                    for (int nj = 0; nj < 4; ++nj)
                        acc[mi][nj] = __builtin_amdgcn_mfma_f32_16x16x32_bf16(
                            af[mi], bfv[nj], acc[mi][nj], 0, 0, 0);
            }
        }
    }

    float* rsm = rowsum + m * NF;
    #pragma unroll
    for (int j = 0; j < 4; ++j) {
        float v = rs[j];
        v += __shfl_xor(v, 1);
        v += __shfl_xor(v, 2);
        v += __shfl_xor(v, 4);
        v += __shfl_xor(v, 8);
        if ((lane & 15) == 0) atomicAdd(rsm + fr + j * 64, v);
    }

    if (w >= 10) return;

    const int rowb = (lane >> 4) * 4;
    const int colb = lane & 15;
    if (use_part) {
        // streaming store of this split's tile: part[(m*16+kc)*10 + w][64*64]
        float* __restrict__ pt = part + (((size_t)m * 16 + kc) * 10 + w) * 4096;
        #pragma unroll
        for (int mi = 0; mi < 4; ++mi)
            #pragma unroll
            for (int nj = 0; nj < 4; ++nj) {
                const int rl = mi * 16 + rowb;
                const int cl = nj * 16 + colb;
                #pragma unroll
                for (int r = 0; r < 4; ++r)
                    pt[(size_t)(rl + r) * 64 + cl] = acc[mi][nj][r];
            }
    } else {
        float* g = gram + (size_t)m * NF * NF;
        #pragma unroll
        for (int mi = 0; mi < 4; ++mi)
            #pragma unroll
            for (int nj = 0; nj < 4; ++nj) {
                const int row = wi + mi * 16 + rowb;
                const int col = wj + nj * 16 + colb;
                #pragma unroll
                for (int r = 0; r < 4; ++r)
                    atomicAdd(g + (size_t)(row + r) * NF + col, acc[mi][nj][r]);
            }
    }
}

// ---------------------------------------------------------------------------
// K1b: reduce split-K partials + fold stats/eps -> PACKED covariance into
// the gram region (first 32896 floats of each matrix slot).
// grid 160 (= 16 m × 10 tiles), 256 threads.
// ---------------------------------------------------------------------------
__global__ __launch_bounds__(256) void k_reduce(const float* __restrict__ part,
                                                const float* __restrict__ rowsum,
                                                float* __restrict__ covP) {
    const int m  = blockIdx.x / 10;
    const int tt = blockIdx.x % 10;
    int ti, tj;
    tri_map(tt, ti, tj);
    __shared__ float smr[64], smc[64];
    const float* __restrict__ rsb = rowsum + m * NF;
    if (threadIdx.x < 64)        smr[threadIdx.x]      = rsb[ti * 64 + threadIdx.x];
    else if (threadIdx.x < 128)  smc[threadIdx.x - 64] = rsb[tj * 64 + threadIdx.x - 64];
    __syncthreads();
    const float invLn  = 1.f / (float)LSP;
    const float invLm1 = 1.f / (float)(LSP - 1);
    const float* __restrict__ base = part + ((size_t)m * 16 * 10 + tt) * 4096;
    float* __restrict__ cp = covP + (size_t)m * NF * NF;   // packed triangle
    for (int e = threadIdx.x; e < 4096; e += 256) {
        const int rl = e >> 6, cl = e & 63;
        const int r = ti * 64 + rl, c = tj * 64 + cl;
        if (c <= r) {
            float s = 0.f;
            #pragma unroll
            for (int sp = 0; sp < 16; ++sp)
                s += base[(size_t)sp * 10 * 4096 + e];
            float v = (s - smr[rl] * smc[cl] * invLn) * invLm1;
            if (c == r) v += EPS_J;
            cp[((r * (r + 1)) >> 1) + c] = v;
        }
    }
}

// ---------------------------------------------------------------------------
// K2 helpers
// ---------------------------------------------------------------------------
__device__ __forceinline__ void load_split_frag(const float* Lt, int row, int jb,
                                                int lane, bf16x8& h, bf16x8& l) {
    const int koff = (lane >> 4) * 8;
    const int base = ((row * (row + 1)) >> 1) + jb + koff;
    #pragma unroll
    for (int u = 0; u < 8; ++u) {
        const float f = Lt[base + u];
        const short hh = f2bf(f);
        h[u] = hh;
        l[u] = f2bf(f - bf2f(hh));
    }
}

// apply one 16-row stripe: X[stripe] = Pan[stripe]·Wᵀ (both 16-col halves).
// Writes touch ONLY this stripe's rows -> no cross-wave hazard.
__device__ __forceinline__ void apply_stripe(int s, float* Lt, short (*Pb)[40],
                                             const short (*Whs)[40],
                                             const short (*Wls)[40],
                                             int jb, int R0, int lane) {
    bf16x8 ph, pl;
    load_split_frag(Lt, R0 + s * 16 + (lane & 15), jb, lane, ph, pl);
    const int koff = (lane >> 4) * 8;
    #pragma unroll
    for (int half = 0; half < 2; ++half) {
        const int c0 = half * 16;
        bf16x8 wh = *(const bf16x8*)&Whs[c0 + (lane & 15)][koff];
        bf16x8 wl = *(const bf16x8*)&Wls[c0 + (lane & 15)][koff];
        f32x4 acc = {0.f, 0.f, 0.f, 0.f};
        acc = __builtin_amdgcn_mfma_f32_16x16x32_bf16(ph, wh, acc, 0, 0, 0);
        acc = __builtin_amdgcn_mfma_f32_16x16x32_bf16(pl, wh, acc, 0, 0, 0);
        acc = __builtin_amdgcn_mfma_f32_16x16x32_bf16(ph, wl, acc, 0, 0, 0);
        const int col  = c0 + (lane & 15);
        const int rowb = s * 16 + (lane >> 4) * 4;
        #pragma unroll
        for (int rg = 0; rg < 4; ++rg) {
            const int rr  = rowb + rg;
            const int row = R0 + rr;
            Lt[((row * (row + 1)) >> 1) + jb + col] = acc[rg];
            Pb[rr][col] = f2bf(acc[rg]);
        }
    }
}

// trailing syrk tile tt (triangular enum): C -= X·Xᵀ, RMW in LDS.
__device__ __forceinline__ void syrk_tile(int tt, float* Lt, const short (*Pb)[40],
                                          int R0, int lane) {
    int tr = (int)((sqrtf(8.f * (float)tt + 1.f) - 1.f) * 0.5f);
    while ((tr + 1) * (tr + 2) / 2 <= tt) ++tr;
    while (tr * (tr + 1) / 2 > tt) --tr;
    const int tc = tt - tr * (tr + 1) / 2;
    const int r0 = tr * 16, c0 = tc * 16;
    bf16x8 af  = *(const bf16x8*)&Pb[r0 + (lane & 15)][(lane >> 4) * 8];
    bf16x8 bfv = *(const bf16x8*)&Pb[c0 + (lane & 15)][(lane >> 4) * 8];
    f32x4 accv = {0.f, 0.f, 0.f, 0.f};
    accv = __builtin_amdgcn_mfma_f32_16x16x32_bf16(af, bfv, accv, 0, 0, 0);
    const int col  = R0 + c0 + (lane & 15);
    const int rowb = R0 + r0 + (lane >> 4) * 4;
    if (tr != tc) {
        #pragma unroll
        for (int rg = 0; rg < 4; ++rg) {
            const int row = rowb + rg;
            Lt[((row * (row + 1)) >> 1) + col] -= accv[rg];
        }
    } else {
        #pragma unroll
        for (int rg = 0; rg < 4; ++rg) {
            const int row = rowb + rg;
            if (col <= row)
                Lt[((row * (row + 1)) >> 1) + col] -= accv[rg];
        }
    }
}

// factor 32x32 diag block at jb (lanes 0..31, lane r = row r) and, if doW,
// compute W = inv(L_diag) column-per-lane entirely in registers (readlane
// broadcasts) and publish split-bf16.
__device__ __forceinline__ void factor_and_winv(int jb, bool doW, float* Lt,
                                                short (*Whs)[40], short (*Wls)[40],
                                                int r) {
    const int rbase = (((jb + r) * (jb + r + 1)) >> 1) + jb;
    float a[32];
    #pragma unroll
    for (int c = 0; c < 32; ++c)
        a[c] = (c <= r) ? Lt[rbase + c] : 0.f;
    #pragma unroll
    for (int j = 0; j < 32; ++j) {
        const float ajv = a[j];                       // unscaled column j
        const float d   = rlane(ajv, j);              // pivot (uniform)
        const float rd  = __builtin_amdgcn_rcpf(d);
        const float rs  = __builtin_amdgcn_rsqf(d);
        const float sc  = ajv * rd;                   // A[r][j]/d
        #pragma unroll
        for (int c = j + 1; c < 32; ++c)
            a[c] -= sc * rlane(ajv, c);               // -= A[r][j]·A[c][j]/d
        a[j] = ajv * rs;                              // final L[r][j]
    }
    #pragma unroll
    for (int c = 0; c < 32; ++c)
        if (c <= r) Lt[rbase + c] = a[c];
    if (doW) {
        const int k = r;                              // lane k -> column k of W
        float wcol[32];
        #pragma unroll
        for (int c = 0; c < 32; ++c) {
            float s = (c == k) ? 1.f : 0.f;
            #pragma unroll
            for (int j = 0; j < c; ++j)
                s -= rlane(a[j], c) * wcol[j];        // L[c][j] broadcast
            wcol[c] = s * __builtin_amdgcn_rcpf(rlane(a[c], c));
            const short hh = f2bf(wcol[c]);
            Whs[c][k] = hh;
            Wls[c][k] = f2bf(wcol[c] - bf2f(hh));
        }
    }
}

// ---------------------------------------------------------------------------
// K2: Cholesky, LDS-resident packed triangle, 1 block (16 waves) per matrix.
// Pipeline per panel p (2 barriers):
//   A: all waves apply X = Pan·Wᵀ (one 16-row stripe per wave)
//   B: wave0 {syrk next-diag tiles 0,1,2; factor+inv next diag} ||
//      waves1-15 {remaining trailing syrk tiles}
// ---------------------------------------------------------------------------
__global__ __launch_bounds__(1024, 4) void k_chol(float* __restrict__ Lg_all,
                                                  const float* __restrict__ rowsum,
                                                  float* __restrict__ LcT_all,
                                                  float* __restrict__ mean_all,
                                                  int use_part) {
    const int m = blockIdx.x;
    float* __restrict__ Lg  = Lg_all + (size_t)m * NF * NF;   // aliases gram[m]
    float* __restrict__ LcT = (m < BATCH) ? (LcT_all + (size_t)m * NF * NF) : nullptr;

    __shared__ float Lt[32896];     // packed lower triangle (131584 B)
    __shared__ float Sm[NF];        // fallback path only
    __shared__ short Whs[32][40];   // W = inv(diag block), bf16 hi
    __shared__ short Wls[32][40];   // W lo residual
    __shared__ short Pb[224][40];   // solved panel, bf16, 80B rows

    const int t    = threadIdx.x;
    const int lane = t & 63;
    const int wv   = t >> 6;

    if (t < NF) {
        float s = rowsum[m * NF + t];
        Sm[t] = s;
        mean_all[m * NF + t] = s * (1.f / (float)LSP);
    }
    __syncthreads();

    if (use_part) {
        // packed cov already formed by k_reduce -> straight copy to LDS
        for (int i4 = t; i4 < 8224; i4 += 1024)
            ((f32x4*)Lt)[i4] = ((const f32x4*)Lg)[i4];
    } else {
        const float invLn  = 1.f / (float)LSP;
        const float invLm1 = 1.f / (float)(LSP - 1);
        for (int idx = t; idx < NF * NF; idx += 1024) {
            const int r = idx >> 8, c = idx & 255;
            if (c <= r) {
                float v = (Lg[idx] - Sm[r] * Sm[c] * invLn) * invLm1;
                if (c == r) v += EPS_J;
                Lt[((r * (r + 1)) >> 1) + c] = v;
            }
        }
    }
    __syncthreads();

    // F(0): factor first diag + W
    if (t < 32) factor_and_winv(0, true, Lt, Whs, Wls, t);
    __syncthreads();

    for (int p = 0; p < 7; ++p) {
        const int jb = p * 32;
        const int R0 = jb + 32;
        const int R  = NF - R0;          // 224..32
        const int nS = R >> 4;           // 16-row stripes (14..2)

        // ---- A: apply panel ----
        if (wv < nS) apply_stripe(wv, Lt, Pb, Whs, Wls, jb, R0, lane);
        __syncthreads();

        // ---- B: trailing syrk || next factor ----
        const int ntt = nS * (nS + 1) / 2;
        if (wv == 0) {
            syrk_tile(0, Lt, Pb, R0, lane);   // (0,0)
            syrk_tile(1, Lt, Pb, R0, lane);   // (1,0)
            syrk_tile(2, Lt, Pb, R0, lane);   // (1,1)  -> next diag updated
            if (t < 32) factor_and_winv(R0, (R - 32) > 0, Lt, Whs, Wls, t);
        } else {
            for (int tt = 2 + wv; tt < ntt; tt += 15)
                syrk_tile(tt, Lt, Pb, R0, lane);
        }
        __syncthreads();
    }

    // epilogue: one-shot write-out
    if (LcT) {
        // content: LcT[c][r] = L[r][c] (r >= c) — k_solveT reads LcT rows.
        for (int idx = t; idx < NF * NF; idx += 1024) {
            const int cc = idx >> 8, rr = idx & 255;
            if (rr >= cc) LcT[idx] = Lt[((rr * (rr + 1)) >> 1) + cc];
        }
    } else {
        // style: lower triangle back into Lg (= Ls); upper never read.
        for (int idx = t; idx < NF * NF; idx += 1024) {
            const int r = idx >> 8, c = idx & 255;
            if (c <= r) Lg[idx] = Lt[((r * (r + 1)) >> 1) + c];
        }
    }
}

// ---------------------------------------------------------------------------
// K3: solve T·Lc = Ls per row of T (T lower-triangular), write Tbf (bf16)
// and bias[i] = s_mean[i] − Σ_k T[i,k]·c_mean[k]. One wave per (b, i).
// grid 512 x 256 thr (4 waves). Lc read via LcT (contiguous columns).
// ---------------------------------------------------------------------------
__global__ __launch_bounds__(256) void k_solveT(const float* __restrict__ Lg_all,
                                                const float* __restrict__ LcT_all,
                                                const float* __restrict__ mean_all,
                                                short* __restrict__ Tbf,
                                                float* __restrict__ bias) {
    const int lane = threadIdx.x & 63;
    const int wv   = threadIdx.x >> 6;
    const int task = blockIdx.x * 4 + wv;
    const int b    = task >> 8;
    const int i    = task & 255;
    const float* __restrict__ Ls  = Lg_all + (size_t)(BATCH + b) * NF * NF + (size_t)i * NF;
    const float* __restrict__ LcT = LcT_all + (size_t)b * NF * NF;

    __shared__ float vbuf[4][NF];
    float* vb = vbuf[wv];
    for (int k = lane; k < NF; k += 64) vb[k] = 0.f;

    int j = i;
    for (; j >= 1; j -= 2) {
        const float* __restrict__ r0 = LcT + (size_t)j * NF;        // Lc[k][j]
        const float* __restrict__ r1 = r0 - NF;                     // Lc[k][j-1]
        float s0 = 0.f, s1 = 0.f;
        for (int k = j + 1 + lane; k <= i; k += 64) {
            const float tk = vb[k];
            s0 += tk * r0[k];
            s1 += tk * r1[k];
        }
        #pragma unroll
        for (int mm = 32; mm >= 1; mm >>= 1) {
            s0 += __shfl_xor(s0, mm);
            s1 += __shfl_xor(s1, mm);
        }
        if (lane == 0) {
            const float tj  = (Ls[j] - s0) / r0[j];
            const float tjm = (Ls[j - 1] - s1 - tj * r1[j]) / r1[j - 1];
            vb[j]     = tj;
            vb[j - 1] = tjm;
        }
    }
    if (j == 0) {
        const float* __restrict__ r0 = LcT;
        float s0 = 0.f;
        for (int k = 1 + lane; k <= i; k += 64) s0 += vb[k] * r0[k];
        #pragma unroll
        for (int mm = 32; mm >= 1; mm >>= 1) s0 += __shfl_xor(s0, mm);
        if (lane == 0) vb[0] = (Ls[0] - s0) / r0[0];
    }

    // bias[i] = s_mean[i] − Σ T[i,k]·c_mean[k]
    const float* __restrict__ cm  = mean_all + b * NF;
    const float* __restrict__ smn = mean_all + (BATCH + b) * NF;
    float dot = 0.f;
    for (int k = lane; k < NF; k += 64) dot += vb[k] * cm[k];
    #pragma unroll
    for (int mm = 32; mm >= 1; mm >>= 1) dot += __shfl_xor(dot, mm);
    if (lane == 0) bias[b * NF + i] = smn[i] - dot;

    short* __restrict__ Tr = Tbf + (size_t)b * NF * NF + (size_t)i * NF;
    const int k4 = lane * 4;
    short4v o = { f2bf(vb[k4]), f2bf(vb[k4 + 1]), f2bf(vb[k4 + 2]), f2bf(vb[k4 + 3]) };
    *(short4v*)&Tr[k4] = o;
}

// ---------------------------------------------------------------------------
// K4: out = T·xc + bias. bf16 MFMA, tile 256(i) x 64(l), K=256.
// grid (256 l-tiles, 8 batches), 256 thr (4 waves of 64x64).
// ---------------------------------------------------------------------------
__global__ __launch_bounds__(256) void k_out(const float* __restrict__ cont,
                                             const short* __restrict__ Tbf,
                                             const float* __restrict__ bias,
                                             float* __restrict__ out) {
    const int b  = blockIdx.y;
    const int l0 = blockIdx.x * 64;
    const float* __restrict__ X  = cont + (size_t)b * NF * LSP;
    const short* __restrict__ Tb = Tbf + (size_t)b * NF * NF;
    float* __restrict__ O = out + (size_t)b * NF * LSP;

    __shared__ short a_s[256][72];
    __shared__ short b_s[64][72];
    __shared__ float bias_s[NF];

    const int t    = threadIdx.x;
    const int lane = t & 63;
    const int w    = t >> 6;

    bias_s[t] = bias[b * NF + t];

    f32x4 acc[4][4];
    #pragma unroll
    for (int i = 0; i < 4; ++i)
        #pragma unroll
        for (int j = 0; j < 4; ++j) { f32x4 z = {0.f,0.f,0.f,0.f}; acc[i][j] = z; }

    const int kb = (t >> 4) * 4;
    const int lb = (t & 15) * 4;
    const int fr = t >> 4;
    const int fc = (t & 15) * 4;

    float4 xr[4];
    #pragma unroll
    for (int r = 0; r < 4; ++r)
        xr[r] = *(const float4*)(X + (size_t)(kb + r) * LSP + l0 + lb);

    for (int step = 0; step < 4; ++step) {
        const int k0 = step * 64;
        __syncthreads();
        #pragma unroll
        for (int s2 = 0; s2 < 16; ++s2) {
            const int row = fr + s2 * 16;
            *(short4v*)&a_s[row][fc] = *(const short4v*)(Tb + (size_t)row * NF + k0 + fc);
        }
        {
            short4v c0v = { f2bf(xr[0].x), f2bf(xr[1].x), f2bf(xr[2].x), f2bf(xr[3].x) };
            short4v c1v = { f2bf(xr[0].y), f2bf(xr[1].y), f2bf(xr[2].y), f2bf(xr[3].y) };
            short4v c2v = { f2bf(xr[0].z), f2bf(xr[1].z), f2bf(xr[2].z), f2bf(xr[3].z) };
            short4v c3v = { f2bf(xr[0].w), f2bf(xr[1].w), f2bf(xr[2].w), f2bf(xr[3].w) };
            *(short4v*)&b_s[lb + 0][kb] = c0v;
            *(short4v*)&b_s[lb + 1][kb] = c1v;
            *(short4v*)&b_s[lb + 2][kb] = c2v;
            *(short4v*)&b_s[lb + 3][kb] = c3v;
        }
        __syncthreads();
        if (step < 3) {
            const int k0n = k0 + 64;
            #pragma unroll
            for (int r = 0; r < 4; ++r)
                xr[r] = *(const float4*)(X + (size_t)(k0n + kb + r) * LSP + l0 + lb);
        }
        #pragma unroll
        for (int ks = 0; ks < 2; ++ks) {
            const int kk   = ks * 32 + (lane >> 4) * 8;
            const int rsel = lane & 15;
            bf16x8 af[4], bfv[4];
            #pragma unroll
            for (int mi = 0; mi < 4; ++mi)
                af[mi] = *(const bf16x8*)&a_s[w * 64 + mi * 16 + rsel][kk];
            #pragma unroll
            for (int nj = 0; nj < 4; ++nj)
                bfv[nj] = *(const bf16x8*)&b_s[nj * 16 + rsel][kk];
            #pragma unroll
            for (int mi = 0; mi < 4; ++mi)
                #pragma unroll
                for (int nj = 0; nj < 4; ++nj)
                    acc[mi][nj] = __builtin_amdgcn_mfma_f32_16x16x32_bf16(
                        af[mi], bfv[nj], acc[mi][nj], 0, 0, 0);
        }
    }

    #pragma unroll
    for (int mi = 0; mi < 4; ++mi) {
        const int row = w * 64 + mi * 16 + (lane >> 4) * 4;
        #pragma unroll
        for (int nj = 0; nj < 4; ++nj) {
            const int col = l0 + nj * 16 + (lane & 15);
            #pragma unroll
            for (int r = 0; r < 4; ++r)
                O[(size_t)(row + r) * LSP + col] = acc[mi][nj][r] + bias_s[row + r];
        }
    }
}

// ---------------------------------------------------------------------------
extern "C" void kernel_launch(void* const* d_in, const int* in_sizes, int n_in,
                              void* d_out, int out_size, void* d_ws, size_t ws_size,
                              hipStream_t stream) {
    (void)in_sizes; (void)n_in; (void)out_size;
    const float* cont = (const float*)d_in[0];
    const float* styl = (const float*)d_in[1];
    float* out = (float*)d_out;

    float* ws       = (float*)d_ws;
    float* gram     = ws;                         // 16*65536 f32 — packed cov, then Lg
    float* rowsum   = gram + 16 * 65536;          // 16*256
    float* mean_all = rowsum + 4096;              // 16*256
    float* bias     = mean_all + 4096;            // 8*256
    float* LcT      = bias + 2048;                // 8*65536 f32 (2 MB)
    short* Tbf      = (short*)(LcT + 8 * 65536);  // 8*65536 bf16 (1 MB)
    float* part     = (float*)(Tbf + 8 * 65536);  // 16*16*10*4096 f32 (41.9 MB)

    const size_t need = ((size_t)((char*)(part + (size_t)16 * 16 * 10 * 4096)
                                  - (char*)ws));
    const int use_part = (ws_size >= need) ? 1 : 0;

    if (use_part) {
        hipMemsetAsync(rowsum, 0, (size_t)4096 * sizeof(float), stream);
    } else {
        hipMemsetAsync(gram, 0, (size_t)(16 * 65536 + 4096) * sizeof(float), stream);
    }

    k_cov   <<<dim3(16, 16), 1024, 0, stream>>>(cont, styl, gram, rowsum, part, use_part);
    if (use_part)
        k_reduce<<<160, 256, 0, stream>>>(part, rowsum, gram);
    k_chol  <<<16,           1024, 0, stream>>>(gram, rowsum, LcT, mean_all, use_part);
    k_solveT<<<512,          256,  0, stream>>>(gram, LcT, mean_all, Tbf, bias);
    k_out   <<<dim3(256, 8), 256,  0, stream>>>(cont, Tbf, bias, out);
}